// Round 9
// baseline (3872.105 us; speedup 1.0000x reference)
//
#include <hip/hip_runtime.h>

#define BB 32
#define TT 256
#define HH 512
#define NBLK 64
#define ALD 1032   // A_lds padded row stride in elements (1024 + 8)
#define ZLD 68     // z_lds padded row stride in floats (64 + 4)

typedef float    f32x4 __attribute__((ext_vector_type(4)));
typedef int      i32x4 __attribute__((ext_vector_type(4)));
typedef _Float16 f16x8 __attribute__((ext_vector_type(8)));

__device__ __forceinline__ unsigned short f2h(float f) {   // f32 -> f16 bits (RNE)
  union { _Float16 h; unsigned short u; } v; v.h = (_Float16)f; return v.u;
}
__device__ __forceinline__ int pkh2(float a, float b) {    // pack two f16
  return (int)((unsigned int)f2h(a) | ((unsigned int)f2h(b) << 16));
}
__device__ __forceinline__ float sigm(float x) { return 1.f / (1.f + __expf(-x)); }
__device__ __forceinline__ float tanh_(float x) {
  float ax = fabsf(x);
  float e = __expf(-2.f * ax);
  float r = (1.f - e) / (1.f + e);
  return copysignf(r, x);
}

__global__ void zero_ws_kernel(unsigned int* p, int nwords) {
  int i = blockIdx.x * 256 + threadIdx.x;
  if (i < nwords) p[i] = 0u;
}

// 64 persistent blocks: blk 0..31 -> layer 0, blk 32..63 -> layer 1 (one step behind).
// Each block owns 16 hidden units; wave w handles gate w (i,f,g,o) for those units.
// Round-8 skeleton; ONLY delta: inline-asm MFMA -> compiler intrinsic (hazard-safe).
__global__ __launch_bounds__(256, 1) void lstm_enc_kernel(
    const int* __restrict__ tokens,
    const int* __restrict__ lengths,
    const float* __restrict__ emb,     // [V][512] fp32
    const float* __restrict__ Wx,      // [2][512][2048] fp32
    const float* __restrict__ Wh,      // [2][512][2048] fp32
    const float* __restrict__ bias,    // [2][2048] fp32
    float* __restrict__ out,           // y [32][256][512] ++ c [32][512] ++ h [32][512] fp32
    unsigned short* __restrict__ ws_y, // [32][256][512] layer-0 outputs (f16 bits)
    unsigned short* __restrict__ ws_h, // [2 layers][2 bufs][32][512] (f16 bits)
    unsigned int* __restrict__ bar)
{
  const int tid   = threadIdx.x;
  const int blk   = blockIdx.x;
  const int layer = blk >> 5;    // 0 or 1
  const int lblk  = blk & 31;    // hidden units [lblk*16, lblk*16+16)
  const int wave  = tid >> 6;    // gate index 0..3 (i,f,g,o)
  const int lane  = tid & 63;

  __shared__ unsigned short Alds[32 * ALD];   // [32 rows][1024 cols]: [x_t | h_prev] f16
  __shared__ float zlds[32 * ZLD];            // [32 rows][64 cols] fp32

  // ---- preload stacked-weight B fragments into registers (K = 1024, N = 16 per wave)
  const int nloc  = lane & 15;
  const int gcol  = wave * HH + lblk * 16 + nloc;   // column in [0,2048)
  const int krow0 = (lane >> 4) * 8;
  const float* WxL = Wx + (size_t)layer * HH * 2048;
  const float* WhL = Wh + (size_t)layer * HH * 2048;
  f16x8 breg[32];
#pragma unroll
  for (int s = 0; s < 32; ++s) {
    const float* base = (s < 16)
        ? (WxL + (size_t)(s * 32 + krow0) * 2048 + gcol)
        : (WhL + (size_t)((s - 16) * 32 + krow0) * 2048 + gcol);
    f16x8 v;
    v[0] = (_Float16)base[0 * 2048];
    v[1] = (_Float16)base[1 * 2048];
    v[2] = (_Float16)base[2 * 2048];
    v[3] = (_Float16)base[3 * 2048];
    v[4] = (_Float16)base[4 * 2048];
    v[5] = (_Float16)base[5 * 2048];
    v[6] = (_Float16)base[6 * 2048];
    v[7] = (_Float16)base[7 * 2048];
    breg[s] = v;
  }

  // ---- per-thread persistent elementwise state: 2 (batch,unit) pairs
  const int ew_j  = tid & 15;          // unit-within-block
  const int ew_b0 = tid >> 4;          // batch 0..15 (pair 1 adds +16)
  const int unit  = lblk * 16 + ew_j;  // global hidden unit
  const int len0  = lengths[ew_b0];
  const int len1  = lengths[ew_b0 + 16];
  const float bI = bias[layer * 2048 +        unit];
  const float bF = bias[layer * 2048 +  512 + unit];
  const float bG = bias[layer * 2048 + 1024 + unit];
  const float bO = bias[layer * 2048 + 1536 + unit];
  float c0 = 0.f, h0v = 0.f, c1 = 0.f, h1v = 0.f;

  unsigned short* hbuf = ws_h + (size_t)layer * 2 * BB * HH;

  for (int it = 0;; ++it) {
    const int t = (layer == 0) ? it : (it - 1);
    const bool active = (t >= 0) && (t < TT);

    if (active) {
      // ---- stage A = [x_t | h_{t-1}] (f16) into LDS, 16B per thread x 16
      const unsigned short* hsrc = hbuf + (size_t)(t & 1) * BB * HH;
#pragma unroll
      for (int i = 0; i < 16; ++i) {
        int u   = tid + i * 256;        // 0..4095 16B-units
        int row = u >> 7;               // batch row 0..31
        int ce  = (u & 127) * 8;        // element col 0..1016
        i32x4 w;
        if (ce < HH) {
          if (layer == 0) {
            int tok = tokens[row * TT + t];
            const float* src = emb + (size_t)tok * HH + ce;
            f32x4 lo = *(const f32x4*)src;
            f32x4 hi = *(const f32x4*)(src + 4);
            w[0] = pkh2(lo[0], lo[1]); w[1] = pkh2(lo[2], lo[3]);
            w[2] = pkh2(hi[0], hi[1]); w[3] = pkh2(hi[2], hi[3]);
          } else {
            w = *(const i32x4*)(ws_y + ((size_t)row * TT + t) * HH + ce);
          }
        } else {
          w = *(const i32x4*)(hsrc + row * HH + (ce - HH));
        }
        *(i32x4*)(&Alds[row * ALD + ce]) = w;
      }
    }
    __syncthreads();

    if (active) {
      // ---- z[32 x 16cols] for this wave's gate: 64 intrinsic MFMAs over K=1024
      f32x4 acc0 = {0.f, 0.f, 0.f, 0.f};
      f32x4 acc1 = {0.f, 0.f, 0.f, 0.f};
      const _Float16* a0p = (const _Float16*)&Alds[nloc * ALD + krow0];
      const _Float16* a1p = a0p + 16 * ALD;
#pragma unroll
      for (int s = 0; s < 32; ++s) {
        f16x8 a0 = *(const f16x8*)(a0p + s * 32);
        f16x8 a1 = *(const f16x8*)(a1p + s * 32);
        acc0 = __builtin_amdgcn_mfma_f32_16x16x32_f16(a0, breg[s], acc0, 0, 0, 0);
        acc1 = __builtin_amdgcn_mfma_f32_16x16x32_f16(a1, breg[s], acc1, 0, 0, 0);
      }
      const int zc = wave * 16 + nloc;
      const int zr = (lane >> 4) * 4;
#pragma unroll
      for (int r = 0; r < 4; ++r) {
        zlds[(zr + r) * ZLD + zc]        = acc0[r];
        zlds[(16 + zr + r) * ZLD + zc]   = acc1[r];
      }
    }
    __syncthreads();

    if (active) {
      unsigned short* hdst = hbuf + (size_t)((t + 1) & 1) * BB * HH;
#pragma unroll
      for (int p = 0; p < 2; ++p) {
        const int b   = ew_b0 + p * 16;
        const int len = p ? len1 : len0;
        float zi = zlds[b * ZLD +      ew_j] + bI;
        float zf = zlds[b * ZLD + 16 + ew_j] + bF;
        float zg = zlds[b * ZLD + 32 + ew_j] + bG;
        float zo = zlds[b * ZLD + 48 + ew_j] + bO;
        float cc = p ? c1 : c0;
        float hh = p ? h1v : h0v;
        float nc = sigm(zf) * cc + sigm(zi) * tanh_(zg);
        float nh = sigm(zo) * tanh_(nc);
        if (t < len) { cc = nc; hh = nh; }
        if (p) { c1 = cc; h1v = hh; } else { c0 = cc; h0v = hh; }
        unsigned short hb = f2h(hh);
        hdst[b * HH + unit] = hb;
        if (layer == 0) ws_y[((size_t)b * TT + t) * HH + unit] = hb;
        else            out [((size_t)b * TT + t) * HH + unit] = hh;
      }
    }

    if (it == TT) break;

    // ---- device-scope barrier across all 64 blocks (monotonic counter)
    __syncthreads();
    if (tid == 0) {
      __threadfence();  // release
      __hip_atomic_fetch_add(bar, 1u, __ATOMIC_ACQ_REL, __HIP_MEMORY_SCOPE_AGENT);
      const unsigned int target = (unsigned int)(it + 1) * NBLK;
      while (__hip_atomic_load(bar, __ATOMIC_ACQUIRE, __HIP_MEMORY_SCOPE_AGENT) < target) {
        __builtin_amdgcn_s_sleep(2);
      }
      __threadfence();  // acquire
    }
    __syncthreads();
  }

  if (layer == 1) {
    const size_t coff = (size_t)BB * TT * HH;
    const size_t hoff = coff + (size_t)BB * HH;
    out[coff + (size_t)ew_b0 * HH + unit]        = c0;
    out[hoff + (size_t)ew_b0 * HH + unit]        = h0v;
    out[coff + (size_t)(ew_b0 + 16) * HH + unit] = c1;
    out[hoff + (size_t)(ew_b0 + 16) * HH + unit] = h1v;
  }
}

extern "C" void kernel_launch(void* const* d_in, const int* in_sizes, int n_in,
                              void* d_out, int out_size, void* d_ws, size_t ws_size,
                              hipStream_t stream) {
  (void)in_sizes; (void)n_in; (void)out_size; (void)ws_size;
  const int* tokens  = (const int*)d_in[0];
  const int* lengths = (const int*)d_in[1];
  const float* emb   = (const float*)d_in[2];
  const float* Wx    = (const float*)d_in[3];
  const float* Wh    = (const float*)d_in[4];
  const float* bias  = (const float*)d_in[5];

  // ws layout (round-2-proven footprint, ~8.5 MB):
  //   [0,256)         barrier
  //   [256, +128K)    ws_h [2][2][32][512] u16 (f16 bits)
  //   [+128K, +8M)    ws_y [32][256][512] u16 (f16 bits)
  char* w = (char*)d_ws;
  const size_t HB = (size_t)2 * 2 * BB * HH * 2;      // 131072
  unsigned int*   bar  = (unsigned int*)w;
  unsigned short* ws_h = (unsigned short*)(w + 256);
  unsigned short* ws_y = (unsigned short*)(w + 256 + HB);

  const int zero_words = (int)((256 + HB) / 4);
  hipLaunchKernelGGL(zero_ws_kernel, dim3((zero_words + 255) / 256), dim3(256), 0, stream,
                     (unsigned int*)d_ws, zero_words);
  hipLaunchKernelGGL(lstm_enc_kernel, dim3(NBLK), dim3(256), 0, stream,
                     tokens, lengths, emb, Wx, Wh, bias, (float*)d_out,
                     ws_y, ws_h, bar);
}

// Round 10
// 3409.638 us; speedup vs baseline: 1.1356x; 1.1356x over previous
//
#include <hip/hip_runtime.h>

#define BB 32
#define TT 256
#define HH 512
#define NBLK 64
#define ALD 1032   // A_lds padded row stride in elements (1024 + 8)
#define ZLD 68     // z_lds padded row stride in floats (64 + 4)

typedef float    f32x4 __attribute__((ext_vector_type(4)));
typedef float    f32x2 __attribute__((ext_vector_type(2)));
typedef int      i32x4 __attribute__((ext_vector_type(4)));
typedef _Float16 f16x8 __attribute__((ext_vector_type(8)));
typedef unsigned long long u64;

__device__ __forceinline__ unsigned short f2h(float f) {   // f32 -> f16 bits (RNE)
  union { _Float16 h; unsigned short u; } v; v.h = (_Float16)f; return v.u;
}
__device__ __forceinline__ int pkh2(float a, float b) {    // pack two f16
  return (int)((unsigned int)f2h(a) | ((unsigned int)f2h(b) << 16));
}
__device__ __forceinline__ float sigm(float x) { return 1.f / (1.f + __expf(-x)); }
__device__ __forceinline__ float tanh_(float x) {
  float ax = fabsf(x);
  float e = __expf(-2.f * ax);
  float r = (1.f - e) / (1.f + e);
  return copysignf(r, x);
}

__global__ void zero_ws_kernel(unsigned int* p, int nwords) {
  int i = blockIdx.x * 256 + threadIdx.x;
  if (i < nwords) p[i] = 0u;
}

// 64 persistent blocks: blk 0..31 -> layer 0, blk 32..63 -> layer 1 (one step behind).
// Round-9-proven compute skeleton. Delta (sync layer only): cross-block data moves
// through agent-scope RELAXED atomics (coherent via memory-side L3, no L2 fences);
// barrier = one RELEASE fetch_add + RELAXED spin. No threadfence, no acquire-inv.
__global__ __launch_bounds__(256, 1) void lstm_enc_kernel(
    const int* __restrict__ tokens,
    const int* __restrict__ lengths,
    const float* __restrict__ emb,     // [V][512] fp32
    const float* __restrict__ Wx,      // [2][512][2048] fp32
    const float* __restrict__ Wh,      // [2][512][2048] fp32
    const float* __restrict__ bias,    // [2][2048] fp32
    float* __restrict__ out,           // y [32][256][512] ++ c [32][512] ++ h [32][512] fp32
    unsigned short* __restrict__ ws_y, // [32][256][512] layer-0 outputs (f16 bits)
    unsigned short* __restrict__ ws_h, // [2 layers][2 bufs][32][512] (f16 bits)
    unsigned int* __restrict__ bar)
{
  const int tid   = threadIdx.x;
  const int blk   = blockIdx.x;
  const int layer = blk >> 5;    // 0 or 1
  const int lblk  = blk & 31;    // hidden units [lblk*16, lblk*16+16)
  const int wave  = tid >> 6;    // gate index 0..3 (i,f,g,o)
  const int lane  = tid & 63;

  __shared__ unsigned short Alds[32 * ALD];   // [32 rows][1024 cols]: [x_t | h_prev] f16
  __shared__ float zlds[32 * ZLD];            // [32 rows][64 cols] fp32

  // ---- preload stacked-weight B fragments into registers (K = 1024, N = 16 per wave)
  const int nloc  = lane & 15;
  const int gcol  = wave * HH + lblk * 16 + nloc;   // column in [0,2048)
  const int krow0 = (lane >> 4) * 8;
  const float* WxL = Wx + (size_t)layer * HH * 2048;
  const float* WhL = Wh + (size_t)layer * HH * 2048;
  f16x8 breg[32];
#pragma unroll
  for (int s = 0; s < 32; ++s) {
    const float* base = (s < 16)
        ? (WxL + (size_t)(s * 32 + krow0) * 2048 + gcol)
        : (WhL + (size_t)((s - 16) * 32 + krow0) * 2048 + gcol);
    f16x8 v;
    v[0] = (_Float16)base[0 * 2048];
    v[1] = (_Float16)base[1 * 2048];
    v[2] = (_Float16)base[2 * 2048];
    v[3] = (_Float16)base[3 * 2048];
    v[4] = (_Float16)base[4 * 2048];
    v[5] = (_Float16)base[5 * 2048];
    v[6] = (_Float16)base[6 * 2048];
    v[7] = (_Float16)base[7 * 2048];
    breg[s] = v;
  }

  // ---- per-thread persistent elementwise state: one batch, two adjacent units
  const int jj  = tid & 7;             // unit-pair index 0..7
  const int eb  = tid >> 3;            // batch 0..31
  const int u0  = lblk * 16 + 2 * jj;  // global hidden units u0, u0+1
  const int len = lengths[eb];
  const float bI0 = bias[layer * 2048 +         u0], bI1 = bias[layer * 2048 +         u0 + 1];
  const float bF0 = bias[layer * 2048 +  512 +  u0], bF1 = bias[layer * 2048 +  512 +  u0 + 1];
  const float bG0 = bias[layer * 2048 + 1024 +  u0], bG1 = bias[layer * 2048 + 1024 +  u0 + 1];
  const float bO0 = bias[layer * 2048 + 1536 +  u0], bO1 = bias[layer * 2048 + 1536 +  u0 + 1];
  float cA = 0.f, hA = 0.f, cB = 0.f, hB = 0.f;

  unsigned short* hbuf = ws_h + (size_t)layer * 2 * BB * HH;

  for (int it = 0;; ++it) {
    const int t = (layer == 0) ? it : (it - 1);
    const bool active = (t >= 0) && (t < TT);

    if (active) {
      // ---- stage A = [x_t | h_{t-1}] (f16) into LDS
      const unsigned short* hsrc = hbuf + (size_t)(t & 1) * BB * HH;
      if (layer == 0) {
        // x-half from fp32 embedding (read-only input: normal cached loads)
#pragma unroll
        for (int i = 0; i < 8; ++i) {
          int u   = tid + i * 256;     // 0..2047 16B-units
          int row = u >> 6;
          int ce  = (u & 63) * 8;      // 0..504
          int tok = tokens[row * TT + t];
          const float* src = emb + (size_t)tok * HH + ce;
          f32x4 lo = *(const f32x4*)src;
          f32x4 hi = *(const f32x4*)(src + 4);
          i32x4 w;
          w[0] = pkh2(lo[0], lo[1]); w[1] = pkh2(lo[2], lo[3]);
          w[2] = pkh2(hi[0], hi[1]); w[3] = pkh2(hi[2], hi[3]);
          *(i32x4*)(&Alds[row * ALD + ce]) = w;
        }
      } else {
        // x-half = layer-0 y[t]: coherent (L3) loads, bypass stale L1/L2
#pragma unroll
        for (int i = 0; i < 16; ++i) {
          int u   = tid + i * 256;     // 0..4095 8B-units
          int row = u >> 7;
          int cp  = (u & 127) * 4;     // 0..508
          u64 v = __hip_atomic_load((const u64*)(ws_y + ((size_t)row * TT + t) * HH + cp),
                                    __ATOMIC_RELAXED, __HIP_MEMORY_SCOPE_AGENT);
          *(u64*)(&Alds[row * ALD + cp]) = v;
        }
      }
      // h-half: coherent (L3) loads
#pragma unroll
      for (int i = 0; i < 16; ++i) {
        int u   = tid + i * 256;       // 0..4095 8B-units
        int row = u >> 7;
        int cp  = (u & 127) * 4;       // 0..508
        u64 v = __hip_atomic_load((const u64*)(hsrc + row * HH + cp),
                                  __ATOMIC_RELAXED, __HIP_MEMORY_SCOPE_AGENT);
        *(u64*)(&Alds[row * ALD + 512 + cp]) = v;
      }
    }
    __syncthreads();

    if (active) {
      // ---- z[32 x 16cols] for this wave's gate: 64 intrinsic MFMAs over K=1024
      f32x4 acc0 = {0.f, 0.f, 0.f, 0.f};
      f32x4 acc1 = {0.f, 0.f, 0.f, 0.f};
      const _Float16* a0p = (const _Float16*)&Alds[nloc * ALD + krow0];
      const _Float16* a1p = a0p + 16 * ALD;
#pragma unroll
      for (int s = 0; s < 32; ++s) {
        f16x8 a0 = *(const f16x8*)(a0p + s * 32);
        f16x8 a1 = *(const f16x8*)(a1p + s * 32);
        acc0 = __builtin_amdgcn_mfma_f32_16x16x32_f16(a0, breg[s], acc0, 0, 0, 0);
        acc1 = __builtin_amdgcn_mfma_f32_16x16x32_f16(a1, breg[s], acc1, 0, 0, 0);
      }
      const int zc = wave * 16 + nloc;
      const int zr = (lane >> 4) * 4;
#pragma unroll
      for (int r = 0; r < 4; ++r) {
        zlds[(zr + r) * ZLD + zc]        = acc0[r];
        zlds[(16 + zr + r) * ZLD + zc]   = acc1[r];
      }
    }
    __syncthreads();

    if (active) {
      unsigned short* hdst = hbuf + (size_t)((t + 1) & 1) * BB * HH;
      float zi0 = zlds[eb * ZLD +      2 * jj] + bI0, zi1 = zlds[eb * ZLD +      2 * jj + 1] + bI1;
      float zf0 = zlds[eb * ZLD + 16 + 2 * jj] + bF0, zf1 = zlds[eb * ZLD + 16 + 2 * jj + 1] + bF1;
      float zg0 = zlds[eb * ZLD + 32 + 2 * jj] + bG0, zg1 = zlds[eb * ZLD + 32 + 2 * jj + 1] + bG1;
      float zo0 = zlds[eb * ZLD + 48 + 2 * jj] + bO0, zo1 = zlds[eb * ZLD + 48 + 2 * jj + 1] + bO1;
      float ncA = sigm(zf0) * cA + sigm(zi0) * tanh_(zg0);
      float nhA = sigm(zo0) * tanh_(ncA);
      float ncB = sigm(zf1) * cB + sigm(zi1) * tanh_(zg1);
      float nhB = sigm(zo1) * tanh_(ncB);
      if (t < len) { cA = ncA; hA = nhA; cB = ncB; hB = nhB; }
      unsigned int hp = (unsigned int)f2h(hA) | ((unsigned int)f2h(hB) << 16);
      __hip_atomic_store((unsigned int*)(hdst + eb * HH + u0), hp,
                         __ATOMIC_RELAXED, __HIP_MEMORY_SCOPE_AGENT);
      if (layer == 0) {
        __hip_atomic_store((unsigned int*)(ws_y + ((size_t)eb * TT + t) * HH + u0), hp,
                           __ATOMIC_RELAXED, __HIP_MEMORY_SCOPE_AGENT);
      } else {
        f32x2 o; o[0] = hA; o[1] = hB;
        *(f32x2*)(out + ((size_t)eb * TT + t) * HH + u0) = o;
      }
    }

    if (it == TT) break;

    // ---- device-scope barrier: release RMW + relaxed spin (no cache-inv storms)
    __syncthreads();
    if (tid == 0) {
      __hip_atomic_fetch_add(bar, 1u, __ATOMIC_RELEASE, __HIP_MEMORY_SCOPE_AGENT);
      const unsigned int target = (unsigned int)(it + 1) * NBLK;
      while (__hip_atomic_load(bar, __ATOMIC_RELAXED, __HIP_MEMORY_SCOPE_AGENT) < target) {
        __builtin_amdgcn_s_sleep(1);
      }
    }
    __syncthreads();
  }

  if (layer == 1) {
    const size_t coff = (size_t)BB * TT * HH;
    const size_t hoff = coff + (size_t)BB * HH;
    f32x2 c2; c2[0] = cA; c2[1] = cB;
    f32x2 h2; h2[0] = hA; h2[1] = hB;
    *(f32x2*)(out + coff + (size_t)eb * HH + u0) = c2;
    *(f32x2*)(out + hoff + (size_t)eb * HH + u0) = h2;
  }
}

extern "C" void kernel_launch(void* const* d_in, const int* in_sizes, int n_in,
                              void* d_out, int out_size, void* d_ws, size_t ws_size,
                              hipStream_t stream) {
  (void)in_sizes; (void)n_in; (void)out_size; (void)ws_size;
  const int* tokens  = (const int*)d_in[0];
  const int* lengths = (const int*)d_in[1];
  const float* emb   = (const float*)d_in[2];
  const float* Wx    = (const float*)d_in[3];
  const float* Wh    = (const float*)d_in[4];
  const float* bias  = (const float*)d_in[5];

  // ws layout (proven footprint, ~8.5 MB):
  //   [0,256)         barrier
  //   [256, +128K)    ws_h [2][2][32][512] u16 (f16 bits)
  //   [+128K, +8M)    ws_y [32][256][512] u16 (f16 bits)
  char* w = (char*)d_ws;
  const size_t HB = (size_t)2 * 2 * BB * HH * 2;      // 131072
  unsigned int*   bar  = (unsigned int*)w;
  unsigned short* ws_h = (unsigned short*)(w + 256);
  unsigned short* ws_y = (unsigned short*)(w + 256 + HB);

  const int zero_words = (int)((256 + HB) / 4);
  hipLaunchKernelGGL(zero_ws_kernel, dim3((zero_words + 255) / 256), dim3(256), 0, stream,
                     (unsigned int*)d_ws, zero_words);
  hipLaunchKernelGGL(lstm_enc_kernel, dim3(NBLK), dim3(256), 0, stream,
                     tokens, lengths, emb, Wx, Wh, bias, (float*)d_out,
                     ws_y, ws_h, bar);
}

// Round 11
// 2807.686 us; speedup vs baseline: 1.3791x; 1.2144x over previous
//
#include <hip/hip_runtime.h>

#define BB 32
#define TT 256
#define HH 512
#define NBLK 64
#define ALD 1032   // A_lds padded row stride in elements (1024 + 8)
#define ZLD 68     // z_lds padded row stride in floats (64 + 4)

typedef float    f32x4 __attribute__((ext_vector_type(4)));
typedef float    f32x2 __attribute__((ext_vector_type(2)));
typedef int      i32x4 __attribute__((ext_vector_type(4)));
typedef _Float16 f16x8 __attribute__((ext_vector_type(8)));
typedef unsigned long long u64;

__device__ __forceinline__ unsigned short f2h(float f) {   // f32 -> f16 bits (RNE)
  union { _Float16 h; unsigned short u; } v; v.h = (_Float16)f; return v.u;
}
__device__ __forceinline__ int pkh2(float a, float b) {    // pack two f16
  return (int)((unsigned int)f2h(a) | ((unsigned int)f2h(b) << 16));
}
__device__ __forceinline__ float sigm(float x) { return 1.f / (1.f + __expf(-x)); }
__device__ __forceinline__ float tanh_(float x) {
  float ax = fabsf(x);
  float e = __expf(-2.f * ax);
  float r = (1.f - e) / (1.f + e);
  return copysignf(r, x);
}

__global__ void zero_ws_kernel(unsigned int* p, int nwords) {
  int i = blockIdx.x * 256 + threadIdx.x;
  if (i < nwords) p[i] = 0u;
}

// 64 persistent blocks: blk 0..31 -> layer 0, blk 32..63 -> layer 1 (one step behind).
// Sync: per-layer 32-block barriers (bar0/bar1), RELAXED arrivals (publication via
// __syncthreads' vmcnt drain; data is coherence-point atomics). L0 free-runs; L1
// spins bar0 only before staging ws_y. x-half staged pre-barrier to hide latency.
__global__ __launch_bounds__(256, 1) void lstm_enc_kernel(
    const int* __restrict__ tokens,
    const int* __restrict__ lengths,
    const float* __restrict__ emb,     // [V][512] fp32
    const float* __restrict__ Wx,      // [2][512][2048] fp32
    const float* __restrict__ Wh,      // [2][512][2048] fp32
    const float* __restrict__ bias,    // [2][2048] fp32
    float* __restrict__ out,           // y [32][256][512] ++ c [32][512] ++ h [32][512] fp32
    unsigned short* __restrict__ ws_y, // [32][256][512] layer-0 outputs (f16 bits)
    unsigned short* __restrict__ ws_h, // [2 layers][2 bufs][32][512] (f16 bits)
    unsigned int* __restrict__ bar0,
    unsigned int* __restrict__ bar1)
{
  const int tid   = threadIdx.x;
  const int blk   = blockIdx.x;
  const int layer = blk >> 5;    // 0 or 1
  const int lblk  = blk & 31;    // hidden units [lblk*16, lblk*16+16)
  const int wave  = tid >> 6;    // gate index 0..3 (i,f,g,o)
  const int lane  = tid & 63;

  __shared__ unsigned short Alds[32 * ALD];   // [32 rows][1024 cols]: [x_t | h_prev] f16
  __shared__ float zlds[32 * ZLD];            // [32 rows][64 cols] fp32

  // ---- preload stacked-weight B fragments into registers (K = 1024, N = 16 per wave)
  const int nloc  = lane & 15;
  const int gcol  = wave * HH + lblk * 16 + nloc;   // column in [0,2048)
  const int krow0 = (lane >> 4) * 8;
  const float* WxL = Wx + (size_t)layer * HH * 2048;
  const float* WhL = Wh + (size_t)layer * HH * 2048;
  f16x8 breg[32];
#pragma unroll
  for (int s = 0; s < 32; ++s) {
    const float* base = (s < 16)
        ? (WxL + (size_t)(s * 32 + krow0) * 2048 + gcol)
        : (WhL + (size_t)((s - 16) * 32 + krow0) * 2048 + gcol);
    f16x8 v;
    v[0] = (_Float16)base[0 * 2048];
    v[1] = (_Float16)base[1 * 2048];
    v[2] = (_Float16)base[2 * 2048];
    v[3] = (_Float16)base[3 * 2048];
    v[4] = (_Float16)base[4 * 2048];
    v[5] = (_Float16)base[5 * 2048];
    v[6] = (_Float16)base[6 * 2048];
    v[7] = (_Float16)base[7 * 2048];
    breg[s] = v;
  }

  // ---- per-thread persistent elementwise state: one batch, two adjacent units
  const int jj  = tid & 7;             // unit-pair index 0..7
  const int eb  = tid >> 3;            // batch 0..31
  const int u0  = lblk * 16 + 2 * jj;  // global hidden units u0, u0+1
  const int len = lengths[eb];
  const float bI0 = bias[layer * 2048 +         u0], bI1 = bias[layer * 2048 +         u0 + 1];
  const float bF0 = bias[layer * 2048 +  512 +  u0], bF1 = bias[layer * 2048 +  512 +  u0 + 1];
  const float bG0 = bias[layer * 2048 + 1024 +  u0], bG1 = bias[layer * 2048 + 1024 +  u0 + 1];
  const float bO0 = bias[layer * 2048 + 1536 +  u0], bO1 = bias[layer * 2048 + 1536 +  u0 + 1];
  float cA = 0.f, hA = 0.f, cB = 0.f, hB = 0.f;

  unsigned short* hbuf = ws_h + (size_t)layer * 2 * BB * HH;
  unsigned int* barMine = (layer == 0) ? bar0 : bar1;

  // ---- prologue: layer 0 stages x(0) (emb) into LDS x-half
  if (layer == 0) {
#pragma unroll
    for (int i = 0; i < 8; ++i) {
      int u   = tid + i * 256;
      int row = u >> 6;
      int ce  = (u & 63) * 8;
      int tok = tokens[row * TT + 0];
      const float* src = emb + (size_t)tok * HH + ce;
      f32x4 lo = *(const f32x4*)src;
      f32x4 hi = *(const f32x4*)(src + 4);
      i32x4 w;
      w[0] = pkh2(lo[0], lo[1]); w[1] = pkh2(lo[2], lo[3]);
      w[2] = pkh2(hi[0], hi[1]); w[3] = pkh2(hi[2], hi[3]);
      *(i32x4*)(&Alds[row * ALD + ce]) = w;
    }
  }

  for (int it = 0;; ++it) {
    const int t = (layer == 0) ? it : (it - 1);
    const bool active = (t >= 0) && (t < TT);

    if (active) {
      // ---- stage h-half = h_{t-1} (coherent L3 atomic loads); x-half staged last iter
      const unsigned short* hsrc = hbuf + (size_t)(t & 1) * BB * HH;
#pragma unroll
      for (int i = 0; i < 16; ++i) {
        int u   = tid + i * 256;       // 0..4095 8B-units
        int row = u >> 7;
        int cp  = (u & 127) * 4;       // 0..508
        u64 v = __hip_atomic_load((const u64*)(hsrc + row * HH + cp),
                                  __ATOMIC_RELAXED, __HIP_MEMORY_SCOPE_AGENT);
        *(u64*)(&Alds[row * ALD + 512 + cp]) = v;
      }
    }
    __syncthreads();

    if (active) {
      // ---- z[32 x 16cols] for this wave's gate: 64 intrinsic MFMAs over K=1024
      f32x4 acc0 = {0.f, 0.f, 0.f, 0.f};
      f32x4 acc1 = {0.f, 0.f, 0.f, 0.f};
      const _Float16* a0p = (const _Float16*)&Alds[nloc * ALD + krow0];
      const _Float16* a1p = a0p + 16 * ALD;
#pragma unroll
      for (int s = 0; s < 32; ++s) {
        f16x8 a0 = *(const f16x8*)(a0p + s * 32);
        f16x8 a1 = *(const f16x8*)(a1p + s * 32);
        acc0 = __builtin_amdgcn_mfma_f32_16x16x32_f16(a0, breg[s], acc0, 0, 0, 0);
        acc1 = __builtin_amdgcn_mfma_f32_16x16x32_f16(a1, breg[s], acc1, 0, 0, 0);
      }
      const int zc = wave * 16 + nloc;
      const int zr = (lane >> 4) * 4;
#pragma unroll
      for (int r = 0; r < 4; ++r) {
        zlds[(zr + r) * ZLD + zc]        = acc0[r];
        zlds[(16 + zr + r) * ZLD + zc]   = acc1[r];
      }
    }
    __syncthreads();   // A-tile dead from here; zlds valid

    if (active) {
      unsigned short* hdst = hbuf + (size_t)((t + 1) & 1) * BB * HH;
      float zi0 = zlds[eb * ZLD +      2 * jj] + bI0, zi1 = zlds[eb * ZLD +      2 * jj + 1] + bI1;
      float zf0 = zlds[eb * ZLD + 16 + 2 * jj] + bF0, zf1 = zlds[eb * ZLD + 16 + 2 * jj + 1] + bF1;
      float zg0 = zlds[eb * ZLD + 32 + 2 * jj] + bG0, zg1 = zlds[eb * ZLD + 32 + 2 * jj + 1] + bG1;
      float zo0 = zlds[eb * ZLD + 48 + 2 * jj] + bO0, zo1 = zlds[eb * ZLD + 48 + 2 * jj + 1] + bO1;
      float ncA = sigm(zf0) * cA + sigm(zi0) * tanh_(zg0);
      float nhA = sigm(zo0) * tanh_(ncA);
      float ncB = sigm(zf1) * cB + sigm(zi1) * tanh_(zg1);
      float nhB = sigm(zo1) * tanh_(ncB);
      if (t < len) { cA = ncA; hA = nhA; cB = ncB; hB = nhB; }
      unsigned int hp = (unsigned int)f2h(hA) | ((unsigned int)f2h(hB) << 16);
      __hip_atomic_store((unsigned int*)(hdst + eb * HH + u0), hp,
                         __ATOMIC_RELAXED, __HIP_MEMORY_SCOPE_AGENT);
      if (layer == 0) {
        __hip_atomic_store((unsigned int*)(ws_y + ((size_t)eb * TT + t) * HH + u0), hp,
                           __ATOMIC_RELAXED, __HIP_MEMORY_SCOPE_AGENT);
      } else {
        f32x2 o; o[0] = hA; o[1] = hB;
        *(f32x2*)(out + ((size_t)eb * TT + t) * HH + u0) = o;
      }
    }

    if (it == TT) break;

    // ---- pre-barrier: stage NEXT iteration's x-half (hides load latency)
    if (layer == 0) {
      const int tn = it + 1;
      if (tn < TT) {
#pragma unroll
        for (int i = 0; i < 8; ++i) {
          int u   = tid + i * 256;
          int row = u >> 6;
          int ce  = (u & 63) * 8;
          int tok = tokens[row * TT + tn];
          const float* src = emb + (size_t)tok * HH + ce;
          f32x4 lo = *(const f32x4*)src;
          f32x4 hi = *(const f32x4*)(src + 4);
          i32x4 w;
          w[0] = pkh2(lo[0], lo[1]); w[1] = pkh2(lo[2], lo[3]);
          w[2] = pkh2(hi[0], hi[1]); w[3] = pkh2(hi[2], hi[3]);
          *(i32x4*)(&Alds[row * ALD + ce]) = w;
        }
      }
    } else {
      // next iteration processes t = it; need ws_y[it] -> wait L0 done with step it
      const int tn = it;
      const unsigned int tgt0 = (unsigned int)(it + 1) * 32u;
      while (__hip_atomic_load(bar0, __ATOMIC_RELAXED, __HIP_MEMORY_SCOPE_AGENT) < tgt0) {
        __builtin_amdgcn_s_sleep(1);
      }
#pragma unroll
      for (int i = 0; i < 16; ++i) {
        int u   = tid + i * 256;       // 8B-units
        int row = u >> 7;
        int cp  = (u & 127) * 4;
        u64 v = __hip_atomic_load((const u64*)(ws_y + ((size_t)row * TT + tn) * HH + cp),
                                  __ATOMIC_RELAXED, __HIP_MEMORY_SCOPE_AGENT);
        *(u64*)(&Alds[row * ALD + cp]) = v;
      }
    }

    // ---- per-layer barrier: syncthreads drains vmcnt (publishes atomic stores),
    // then RELAXED arrival + RELAXED spin (no wbl2 / no inv).
    __syncthreads();
    if (tid == 0) {
      __hip_atomic_fetch_add(barMine, 1u, __ATOMIC_RELAXED, __HIP_MEMORY_SCOPE_AGENT);
      const unsigned int target = (unsigned int)(it + 1) * 32u;
      while (__hip_atomic_load(barMine, __ATOMIC_RELAXED, __HIP_MEMORY_SCOPE_AGENT) < target) {
        __builtin_amdgcn_s_sleep(1);
      }
    }
    __syncthreads();
  }

  if (layer == 1) {
    const size_t coff = (size_t)BB * TT * HH;
    const size_t hoff = coff + (size_t)BB * HH;
    f32x2 c2; c2[0] = cA; c2[1] = cB;
    f32x2 h2; h2[0] = hA; h2[1] = hB;
    *(f32x2*)(out + coff + (size_t)eb * HH + u0) = c2;
    *(f32x2*)(out + hoff + (size_t)eb * HH + u0) = h2;
  }
}

extern "C" void kernel_launch(void* const* d_in, const int* in_sizes, int n_in,
                              void* d_out, int out_size, void* d_ws, size_t ws_size,
                              hipStream_t stream) {
  (void)in_sizes; (void)n_in; (void)out_size; (void)ws_size;
  const int* tokens  = (const int*)d_in[0];
  const int* lengths = (const int*)d_in[1];
  const float* emb   = (const float*)d_in[2];
  const float* Wx    = (const float*)d_in[3];
  const float* Wh    = (const float*)d_in[4];
  const float* bias  = (const float*)d_in[5];

  // ws layout (proven footprint, ~8.5 MB):
  //   [0,128)         bar0   [128,256) bar1
  //   [256, +128K)    ws_h [2][2][32][512] u16 (f16 bits)
  //   [+128K, +8M)    ws_y [32][256][512] u16 (f16 bits)
  char* w = (char*)d_ws;
  const size_t HB = (size_t)2 * 2 * BB * HH * 2;      // 131072
  unsigned int*   bar0 = (unsigned int*)w;
  unsigned int*   bar1 = (unsigned int*)(w + 128);
  unsigned short* ws_h = (unsigned short*)(w + 256);
  unsigned short* ws_y = (unsigned short*)(w + 256 + HB);

  const int zero_words = (int)((256 + HB) / 4);
  hipLaunchKernelGGL(zero_ws_kernel, dim3((zero_words + 255) / 256), dim3(256), 0, stream,
                     (unsigned int*)d_ws, zero_words);
  hipLaunchKernelGGL(lstm_enc_kernel, dim3(NBLK), dim3(256), 0, stream,
                     tokens, lengths, emb, Wx, Wh, bias, (float*)d_out,
                     ws_y, ws_h, bar0, bar1);
}

// Round 12
// 2716.953 us; speedup vs baseline: 1.4252x; 1.0334x over previous
//
#include <hip/hip_runtime.h>

#define BB 32
#define TT 256
#define HH 512
#define NBLK 64
#define ALD 1032   // A_lds padded row stride in elements (1024 + 8)
#define ZLD 68     // z_lds padded row stride in floats (64 + 4)
#define FLGSTRIDE 32   // u32s per flag line (128 B)

typedef float    f32x4 __attribute__((ext_vector_type(4)));
typedef float    f32x2 __attribute__((ext_vector_type(2)));
typedef int      i32x4 __attribute__((ext_vector_type(4)));
typedef _Float16 f16x8 __attribute__((ext_vector_type(8)));
typedef unsigned long long u64;

__device__ __forceinline__ unsigned short f2h(float f) {   // f32 -> f16 bits (RNE)
  union { _Float16 h; unsigned short u; } v; v.h = (_Float16)f; return v.u;
}
__device__ __forceinline__ int pkh2(float a, float b) {    // pack two f16
  return (int)((unsigned int)f2h(a) | ((unsigned int)f2h(b) << 16));
}
__device__ __forceinline__ float sigm(float x) { return 1.f / (1.f + __expf(-x)); }
__device__ __forceinline__ float tanh_(float x) {
  float ax = fabsf(x);
  float e = __expf(-2.f * ax);
  float r = (1.f - e) / (1.f + e);
  return copysignf(r, x);
}

__global__ void zero_ws_kernel(unsigned int* p, int nwords) {
  int i = blockIdx.x * 256 + threadIdx.x;
  if (i < nwords) p[i] = 0u;
}

// 64 persistent blocks: blk 0..31 -> layer 0, blk 32..63 -> layer 1 (one step behind).
// Sync: per-block arrival flags (one 128B line each; relaxed agent store = zero
// contention) + parallel lane-poll of the 32 own-layer flags. All cross-block data
// via agent-scope relaxed atomics (coherent at fabric; L1/L2 bypassed).
__global__ __launch_bounds__(256, 1) void lstm_enc_kernel(
    const int* __restrict__ tokens,
    const int* __restrict__ lengths,
    const float* __restrict__ emb,     // [V][512] fp32
    const float* __restrict__ Wx,      // [2][512][2048] fp32
    const float* __restrict__ Wh,      // [2][512][2048] fp32
    const float* __restrict__ bias,    // [2][2048] fp32
    float* __restrict__ out,           // y [32][256][512] ++ c [32][512] ++ h [32][512] fp32
    unsigned short* __restrict__ ws_y, // [32][256][512] layer-0 outputs (f16 bits)
    unsigned short* __restrict__ ws_h, // [2 layers][2 bufs][32][512] (f16 bits)
    unsigned int* __restrict__ flags)  // [64] arrival flags, 128B-strided
{
  const int tid   = threadIdx.x;
  const int blk   = blockIdx.x;
  const int layer = blk >> 5;    // 0 or 1
  const int lblk  = blk & 31;    // hidden units [lblk*16, lblk*16+16)
  const int wave  = tid >> 6;    // gate index 0..3 (i,f,g,o)
  const int lane  = tid & 63;

  __shared__ unsigned short Alds[32 * ALD];   // [32 rows][1024 cols]: [x_t | h_prev] f16
  __shared__ float zlds[32 * ZLD];            // [32 rows][64 cols] fp32

  // ---- preload stacked-weight B fragments into registers (K = 1024, N = 16 per wave)
  const int nloc  = lane & 15;
  const int gcol  = wave * HH + lblk * 16 + nloc;   // column in [0,2048)
  const int krow0 = (lane >> 4) * 8;
  const float* WxL = Wx + (size_t)layer * HH * 2048;
  const float* WhL = Wh + (size_t)layer * HH * 2048;
  f16x8 breg[32];
#pragma unroll
  for (int s = 0; s < 32; ++s) {
    const float* base = (s < 16)
        ? (WxL + (size_t)(s * 32 + krow0) * 2048 + gcol)
        : (WhL + (size_t)((s - 16) * 32 + krow0) * 2048 + gcol);
    f16x8 v;
    v[0] = (_Float16)base[0 * 2048];
    v[1] = (_Float16)base[1 * 2048];
    v[2] = (_Float16)base[2 * 2048];
    v[3] = (_Float16)base[3 * 2048];
    v[4] = (_Float16)base[4 * 2048];
    v[5] = (_Float16)base[5 * 2048];
    v[6] = (_Float16)base[6 * 2048];
    v[7] = (_Float16)base[7 * 2048];
    breg[s] = v;
  }

  // ---- per-thread persistent elementwise state: one batch, two adjacent units
  const int jj  = tid & 7;             // unit-pair index 0..7
  const int eb  = tid >> 3;            // batch 0..31
  const int u0  = lblk * 16 + 2 * jj;  // global hidden units u0, u0+1
  const int len = lengths[eb];
  const float bI0 = bias[layer * 2048 +         u0], bI1 = bias[layer * 2048 +         u0 + 1];
  const float bF0 = bias[layer * 2048 +  512 +  u0], bF1 = bias[layer * 2048 +  512 +  u0 + 1];
  const float bG0 = bias[layer * 2048 + 1024 +  u0], bG1 = bias[layer * 2048 + 1024 +  u0 + 1];
  const float bO0 = bias[layer * 2048 + 1536 +  u0], bO1 = bias[layer * 2048 + 1536 +  u0 + 1];
  float cA = 0.f, hA = 0.f, cB = 0.f, hB = 0.f;

  unsigned short* hbuf = ws_h + (size_t)layer * 2 * BB * HH;
  unsigned int* myFlag = flags + (size_t)blk * FLGSTRIDE;
  // lanes 0..31 of wave 0 poll own-layer flags; L1 additionally polls L0 flags
  unsigned int* pollOwn = flags + (size_t)((layer << 5) + (tid & 31)) * FLGSTRIDE;
  unsigned int* pollL0  = flags + (size_t)(tid & 31) * FLGSTRIDE;

  // ---- prologue: layer 0 stages x(0) (emb) into LDS x-half
  if (layer == 0) {
#pragma unroll
    for (int i = 0; i < 8; ++i) {
      int u   = tid + i * 256;
      int row = u >> 6;
      int ce  = (u & 63) * 8;
      int tok = tokens[row * TT + 0];
      const float* src = emb + (size_t)tok * HH + ce;
      f32x4 lo = *(const f32x4*)src;
      f32x4 hi = *(const f32x4*)(src + 4);
      i32x4 w;
      w[0] = pkh2(lo[0], lo[1]); w[1] = pkh2(lo[2], lo[3]);
      w[2] = pkh2(hi[0], hi[1]); w[3] = pkh2(hi[2], hi[3]);
      *(i32x4*)(&Alds[row * ALD + ce]) = w;
    }
  }

  for (int it = 0;; ++it) {
    const int t = (layer == 0) ? it : (it - 1);
    const bool active = (t >= 0) && (t < TT);

    if (active) {
      // ---- stage h-half = h_{t-1} (coherent fabric atomic loads)
      const unsigned short* hsrc = hbuf + (size_t)(t & 1) * BB * HH;
#pragma unroll
      for (int i = 0; i < 16; ++i) {
        int u   = tid + i * 256;       // 0..4095 8B-units
        int row = u >> 7;
        int cp  = (u & 127) * 4;       // 0..508
        u64 v = __hip_atomic_load((const u64*)(hsrc + row * HH + cp),
                                  __ATOMIC_RELAXED, __HIP_MEMORY_SCOPE_AGENT);
        *(u64*)(&Alds[row * ALD + 512 + cp]) = v;
      }
    }
    __syncthreads();

    if (active) {
      // ---- z[32 x 16cols] for this wave's gate: 64 intrinsic MFMAs over K=1024
      f32x4 acc0 = {0.f, 0.f, 0.f, 0.f};
      f32x4 acc1 = {0.f, 0.f, 0.f, 0.f};
      const _Float16* a0p = (const _Float16*)&Alds[nloc * ALD + krow0];
      const _Float16* a1p = a0p + 16 * ALD;
#pragma unroll
      for (int s = 0; s < 32; ++s) {
        f16x8 a0 = *(const f16x8*)(a0p + s * 32);
        f16x8 a1 = *(const f16x8*)(a1p + s * 32);
        acc0 = __builtin_amdgcn_mfma_f32_16x16x32_f16(a0, breg[s], acc0, 0, 0, 0);
        acc1 = __builtin_amdgcn_mfma_f32_16x16x32_f16(a1, breg[s], acc1, 0, 0, 0);
      }
      const int zc = wave * 16 + nloc;
      const int zr = (lane >> 4) * 4;
#pragma unroll
      for (int r = 0; r < 4; ++r) {
        zlds[(zr + r) * ZLD + zc]        = acc0[r];
        zlds[(16 + zr + r) * ZLD + zc]   = acc1[r];
      }
    }
    __syncthreads();   // A-tile dead from here; zlds valid

    if (active) {
      unsigned short* hdst = hbuf + (size_t)((t + 1) & 1) * BB * HH;
      float zi0 = zlds[eb * ZLD +      2 * jj] + bI0, zi1 = zlds[eb * ZLD +      2 * jj + 1] + bI1;
      float zf0 = zlds[eb * ZLD + 16 + 2 * jj] + bF0, zf1 = zlds[eb * ZLD + 16 + 2 * jj + 1] + bF1;
      float zg0 = zlds[eb * ZLD + 32 + 2 * jj] + bG0, zg1 = zlds[eb * ZLD + 32 + 2 * jj + 1] + bG1;
      float zo0 = zlds[eb * ZLD + 48 + 2 * jj] + bO0, zo1 = zlds[eb * ZLD + 48 + 2 * jj + 1] + bO1;
      float ncA = sigm(zf0) * cA + sigm(zi0) * tanh_(zg0);
      float nhA = sigm(zo0) * tanh_(ncA);
      float ncB = sigm(zf1) * cB + sigm(zi1) * tanh_(zg1);
      float nhB = sigm(zo1) * tanh_(ncB);
      if (t < len) { cA = ncA; hA = nhA; cB = ncB; hB = nhB; }
      unsigned int hp = (unsigned int)f2h(hA) | ((unsigned int)f2h(hB) << 16);
      __hip_atomic_store((unsigned int*)(hdst + eb * HH + u0), hp,
                         __ATOMIC_RELAXED, __HIP_MEMORY_SCOPE_AGENT);
      if (layer == 0) {
        __hip_atomic_store((unsigned int*)(ws_y + ((size_t)eb * TT + t) * HH + u0), hp,
                           __ATOMIC_RELAXED, __HIP_MEMORY_SCOPE_AGENT);
      } else {
        f32x2 o; o[0] = hA; o[1] = hB;
        *(f32x2*)(out + ((size_t)eb * TT + t) * HH + u0) = o;
      }
    }

    if (it == TT) break;

    // ---- pre-barrier: stage NEXT iteration's x-half (hides load latency)
    if (layer == 0) {
      const int tn = it + 1;
      if (tn < TT) {
#pragma unroll
        for (int i = 0; i < 8; ++i) {
          int u   = tid + i * 256;
          int row = u >> 6;
          int ce  = (u & 63) * 8;
          int tok = tokens[row * TT + tn];
          const float* src = emb + (size_t)tok * HH + ce;
          f32x4 lo = *(const f32x4*)src;
          f32x4 hi = *(const f32x4*)(src + 4);
          i32x4 w;
          w[0] = pkh2(lo[0], lo[1]); w[1] = pkh2(lo[2], lo[3]);
          w[2] = pkh2(hi[0], hi[1]); w[3] = pkh2(hi[2], hi[3]);
          *(i32x4*)(&Alds[row * ALD + ce]) = w;
        }
      }
    } else {
      // need ws_y[it] -> wait until all 32 L0 blocks finished step it (flag >= it+1)
      const unsigned int tgt0 = (unsigned int)(it + 1);
      if (tid < 32) {
        while (__hip_atomic_load(pollL0, __ATOMIC_RELAXED, __HIP_MEMORY_SCOPE_AGENT) < tgt0) {
          __builtin_amdgcn_s_sleep(1);
        }
      }
      __syncthreads();
#pragma unroll
      for (int i = 0; i < 16; ++i) {
        int u   = tid + i * 256;       // 8B-units
        int row = u >> 7;
        int cp  = (u & 127) * 4;
        u64 v = __hip_atomic_load((const u64*)(ws_y + ((size_t)row * TT + it) * HH + cp),
                                  __ATOMIC_RELAXED, __HIP_MEMORY_SCOPE_AGENT);
        *(u64*)(&Alds[row * ALD + cp]) = v;
      }
    }

    // ---- per-layer flag barrier: syncthreads drains vmcnt (publishes stores),
    // then contention-free flag store + parallel lane poll.
    __syncthreads();
    if (tid == 0) {
      __hip_atomic_store(myFlag, (unsigned int)(it + 1),
                         __ATOMIC_RELAXED, __HIP_MEMORY_SCOPE_AGENT);
    }
    {
      const unsigned int target = (unsigned int)(it + 1);
      if (tid < 32) {
        while (__hip_atomic_load(pollOwn, __ATOMIC_RELAXED, __HIP_MEMORY_SCOPE_AGENT) < target) {
          __builtin_amdgcn_s_sleep(1);
        }
      }
      __syncthreads();
    }
  }

  if (layer == 1) {
    const size_t coff = (size_t)BB * TT * HH;
    const size_t hoff = coff + (size_t)BB * HH;
    f32x2 c2; c2[0] = cA; c2[1] = cB;
    f32x2 h2; h2[0] = hA; h2[1] = hB;
    *(f32x2*)(out + coff + (size_t)eb * HH + u0) = c2;
    *(f32x2*)(out + hoff + (size_t)eb * HH + u0) = h2;
  }
}

extern "C" void kernel_launch(void* const* d_in, const int* in_sizes, int n_in,
                              void* d_out, int out_size, void* d_ws, size_t ws_size,
                              hipStream_t stream) {
  (void)in_sizes; (void)n_in; (void)out_size; (void)ws_size;
  const int* tokens  = (const int*)d_in[0];
  const int* lengths = (const int*)d_in[1];
  const float* emb   = (const float*)d_in[2];
  const float* Wx    = (const float*)d_in[3];
  const float* Wh    = (const float*)d_in[4];
  const float* bias  = (const float*)d_in[5];

  // ws layout (~8.5 MB):
  //   [0, 8K)         flags [64] x 128B lines
  //   [8K, +128K)     ws_h [2][2][32][512] u16 (f16 bits)
  //   [+128K, +8M)    ws_y [32][256][512] u16 (f16 bits)
  char* w = (char*)d_ws;
  const size_t FB = (size_t)NBLK * FLGSTRIDE * 4;     // 8192
  const size_t HB = (size_t)2 * 2 * BB * HH * 2;      // 131072
  unsigned int*   flags = (unsigned int*)w;
  unsigned short* ws_h  = (unsigned short*)(w + FB);
  unsigned short* ws_y  = (unsigned short*)(w + FB + HB);

  const int zero_words = (int)((FB + HB) / 4);
  hipLaunchKernelGGL(zero_ws_kernel, dim3((zero_words + 255) / 256), dim3(256), 0, stream,
                     (unsigned int*)d_ws, zero_words);
  hipLaunchKernelGGL(lstm_enc_kernel, dim3(NBLK), dim3(256), 0, stream,
                     tokens, lengths, emb, Wx, Wh, bias, (float*)d_out,
                     ws_y, ws_h, flags);
}

// Round 13
// 2240.878 us; speedup vs baseline: 1.7279x; 1.2125x over previous
//
#include <hip/hip_runtime.h>

#define BB 32
#define TT 256
#define HH 512
#define NBLK 64
#define ALD 1032   // A_lds padded row stride in elements (1024 + 8)
#define ZLD 68     // z_lds padded row stride in floats (64 + 4)
#define FLGSTRIDE 32   // u32s per flag line (128 B)

typedef float    f32x4 __attribute__((ext_vector_type(4)));
typedef float    f32x2 __attribute__((ext_vector_type(2)));
typedef int      i32x4 __attribute__((ext_vector_type(4)));
typedef _Float16 f16x8 __attribute__((ext_vector_type(8)));
typedef unsigned long long u64;

__device__ __forceinline__ unsigned short f2h(float f) {   // f32 -> f16 bits (RNE)
  union { _Float16 h; unsigned short u; } v; v.h = (_Float16)f; return v.u;
}
__device__ __forceinline__ int pkh2(float a, float b) {    // pack two f16
  return (int)((unsigned int)f2h(a) | ((unsigned int)f2h(b) << 16));
}
__device__ __forceinline__ float sigm(float x) { return 1.f / (1.f + __expf(-x)); }
__device__ __forceinline__ float tanh_(float x) {
  float ax = fabsf(x);
  float e = __expf(-2.f * ax);
  float r = (1.f - e) / (1.f + e);
  return copysignf(r, x);
}

__global__ void zero_ws_kernel(unsigned int* p, int nwords) {
  int i = blockIdx.x * 256 + threadIdx.x;
  if (i < nwords) p[i] = 0u;
}

// 64 persistent blocks: blk 0..31 -> layer 0, blk 32..63 -> layer 1 (one step behind).
// h recurrence synchronized by INLINE TAGS: each unit-pair published as one atomic
// u64 {tag=t+1, 2xf16}; consumers retry-load until tag==t. One fabric RTT per step,
// no flags/barriers within a layer. L0 keeps a per-step flag only to guard ws_y.
__global__ __launch_bounds__(256, 1) void lstm_enc_kernel(
    const int* __restrict__ tokens,
    const int* __restrict__ lengths,
    const float* __restrict__ emb,     // [V][512] fp32
    const float* __restrict__ Wx,      // [2][512][2048] fp32
    const float* __restrict__ Wh,      // [2][512][2048] fp32
    const float* __restrict__ bias,    // [2][2048] fp32
    float* __restrict__ out,           // y [32][256][512] ++ c [32][512] ++ h [32][512] fp32
    unsigned short* __restrict__ ws_y, // [32][256][512] layer-0 outputs (f16 bits)
    u64* __restrict__ htag,            // [2 layers][2 slots][32][256] tagged h u64
    unsigned int* __restrict__ flags)  // [32] L0 arrival flags, 128B-strided
{
  const int tid   = threadIdx.x;
  const int blk   = blockIdx.x;
  const int layer = blk >> 5;    // 0 or 1
  const int lblk  = blk & 31;    // hidden units [lblk*16, lblk*16+16)
  const int wave  = tid >> 6;    // gate index 0..3 (i,f,g,o)
  const int lane  = tid & 63;

  __shared__ unsigned short Alds[32 * ALD];   // [32 rows][1024 cols]: [x_t | h_prev] f16
  __shared__ float zlds[32 * ZLD];            // [32 rows][64 cols] fp32

  // ---- preload stacked-weight B fragments into registers (K = 1024, N = 16 per wave)
  const int nloc  = lane & 15;
  const int gcol  = wave * HH + lblk * 16 + nloc;   // column in [0,2048)
  const int krow0 = (lane >> 4) * 8;
  const float* WxL = Wx + (size_t)layer * HH * 2048;
  const float* WhL = Wh + (size_t)layer * HH * 2048;
  f16x8 breg[32];
#pragma unroll
  for (int s = 0; s < 32; ++s) {
    const float* base = (s < 16)
        ? (WxL + (size_t)(s * 32 + krow0) * 2048 + gcol)
        : (WhL + (size_t)((s - 16) * 32 + krow0) * 2048 + gcol);
    f16x8 v;
    v[0] = (_Float16)base[0 * 2048];
    v[1] = (_Float16)base[1 * 2048];
    v[2] = (_Float16)base[2 * 2048];
    v[3] = (_Float16)base[3 * 2048];
    v[4] = (_Float16)base[4 * 2048];
    v[5] = (_Float16)base[5 * 2048];
    v[6] = (_Float16)base[6 * 2048];
    v[7] = (_Float16)base[7 * 2048];
    breg[s] = v;
  }

  // ---- per-thread persistent elementwise state: one batch, two adjacent units
  const int jj  = tid & 7;             // unit-pair index 0..7
  const int eb  = tid >> 3;            // batch 0..31
  const int u0  = lblk * 16 + 2 * jj;  // global hidden units u0, u0+1
  const int len = lengths[eb];
  const float bI0 = bias[layer * 2048 +         u0], bI1 = bias[layer * 2048 +         u0 + 1];
  const float bF0 = bias[layer * 2048 +  512 +  u0], bF1 = bias[layer * 2048 +  512 +  u0 + 1];
  const float bG0 = bias[layer * 2048 + 1024 +  u0], bG1 = bias[layer * 2048 + 1024 +  u0 + 1];
  const float bO0 = bias[layer * 2048 + 1536 +  u0], bO1 = bias[layer * 2048 + 1536 +  u0 + 1];
  float cA = 0.f, hA = 0.f, cB = 0.f, hB = 0.f;

  u64* hlay = htag + (size_t)layer * 2 * BB * 256;   // own layer's tagged h, 2 slots
  unsigned int* pollL0 = flags + (size_t)(tid & 31) * FLGSTRIDE;

  // ---- prologue: layer 0 stages x(0) (emb) into LDS x-half
  if (layer == 0) {
#pragma unroll
    for (int i = 0; i < 8; ++i) {
      int u   = tid + i * 256;
      int row = u >> 6;
      int ce  = (u & 63) * 8;
      int tok = tokens[row * TT + 0];
      const float* src = emb + (size_t)tok * HH + ce;
      f32x4 lo = *(const f32x4*)src;
      f32x4 hi = *(const f32x4*)(src + 4);
      i32x4 w;
      w[0] = pkh2(lo[0], lo[1]); w[1] = pkh2(lo[2], lo[3]);
      w[2] = pkh2(hi[0], hi[1]); w[3] = pkh2(hi[2], hi[3]);
      *(i32x4*)(&Alds[row * ALD + ce]) = w;
    }
  }

  for (int it = 0;; ++it) {
    const int t = (layer == 0) ? it : (it - 1);
    const bool active = (t >= 0) && (t < TT);

    if (layer == 1 && active) {
      // ---- guard + stage x-half = ws_y[t] (L0 runs ahead; poll usually satisfied)
      const unsigned int tgt = (unsigned int)(t + 1);
      if (tid < 32) {
        while (__hip_atomic_load(pollL0, __ATOMIC_RELAXED, __HIP_MEMORY_SCOPE_AGENT) < tgt) {
          __builtin_amdgcn_s_sleep(1);
        }
      }
      __syncthreads();
#pragma unroll
      for (int i = 0; i < 16; ++i) {
        int u   = tid + i * 256;       // 8B-units
        int row = u >> 7;
        int cp  = (u & 127) * 4;
        u64 v = __hip_atomic_load((const u64*)(ws_y + ((size_t)row * TT + t) * HH + cp),
                                  __ATOMIC_RELAXED, __HIP_MEMORY_SCOPE_AGENT);
        *(u64*)(&Alds[row * ALD + cp]) = v;
      }
    }

    if (active) {
      // ---- tagged h staging: self-synchronizing loads (tag == t means ready)
      const u64* hsrc = hlay + (size_t)(t & 1) * BB * 256;   // [32][256] u64
      const unsigned int exp = (unsigned int)t;
#pragma unroll
      for (int c = 0; c < 4; ++c) {
        u64 v[8];
        int us[8];
#pragma unroll
        for (int j = 0; j < 8; ++j) {
          us[j] = tid + (c * 8 + j) * 256;
          v[j] = __hip_atomic_load(&hsrc[us[j]], __ATOMIC_RELAXED, __HIP_MEMORY_SCOPE_AGENT);
        }
        bool ok = false;
        while (!ok) {
          ok = true;
#pragma unroll
          for (int j = 0; j < 8; ++j) {
            if ((unsigned int)(v[j] >> 32) != exp) {
              v[j] = __hip_atomic_load(&hsrc[us[j]], __ATOMIC_RELAXED, __HIP_MEMORY_SCOPE_AGENT);
              ok = false;
            }
          }
        }
#pragma unroll
        for (int j = 0; j < 8; ++j) {
          int row = us[j] >> 8, col = us[j] & 255;
          *(unsigned int*)(&Alds[row * ALD + 512 + 2 * col]) = (unsigned int)v[j];
        }
      }
    }
    __syncthreads();

    if (active) {
      // ---- z[32 x 16cols] for this wave's gate: 64 intrinsic MFMAs over K=1024
      f32x4 acc0 = {0.f, 0.f, 0.f, 0.f};
      f32x4 acc1 = {0.f, 0.f, 0.f, 0.f};
      const _Float16* a0p = (const _Float16*)&Alds[nloc * ALD + krow0];
      const _Float16* a1p = a0p + 16 * ALD;
#pragma unroll
      for (int s = 0; s < 32; ++s) {
        f16x8 a0 = *(const f16x8*)(a0p + s * 32);
        f16x8 a1 = *(const f16x8*)(a1p + s * 32);
        acc0 = __builtin_amdgcn_mfma_f32_16x16x32_f16(a0, breg[s], acc0, 0, 0, 0);
        acc1 = __builtin_amdgcn_mfma_f32_16x16x32_f16(a1, breg[s], acc1, 0, 0, 0);
      }
      const int zc = wave * 16 + nloc;
      const int zr = (lane >> 4) * 4;
#pragma unroll
      for (int r = 0; r < 4; ++r) {
        zlds[(zr + r) * ZLD + zc]        = acc0[r];
        zlds[(16 + zr + r) * ZLD + zc]   = acc1[r];
      }
    }
    __syncthreads();   // A-tile dead from here; zlds valid

    if (active) {
      float zi0 = zlds[eb * ZLD +      2 * jj] + bI0, zi1 = zlds[eb * ZLD +      2 * jj + 1] + bI1;
      float zf0 = zlds[eb * ZLD + 16 + 2 * jj] + bF0, zf1 = zlds[eb * ZLD + 16 + 2 * jj + 1] + bF1;
      float zg0 = zlds[eb * ZLD + 32 + 2 * jj] + bG0, zg1 = zlds[eb * ZLD + 32 + 2 * jj + 1] + bG1;
      float zo0 = zlds[eb * ZLD + 48 + 2 * jj] + bO0, zo1 = zlds[eb * ZLD + 48 + 2 * jj + 1] + bO1;
      float ncA = sigm(zf0) * cA + sigm(zi0) * tanh_(zg0);
      float nhA = sigm(zo0) * tanh_(ncA);
      float ncB = sigm(zf1) * cB + sigm(zi1) * tanh_(zg1);
      float nhB = sigm(zo1) * tanh_(ncB);
      if (t < len) { cA = ncA; hA = nhA; cB = ncB; hB = nhB; }
      unsigned int hp = (unsigned int)f2h(hA) | ((unsigned int)f2h(hB) << 16);
      // publish tagged h for step t (consumed at t+1 expecting tag t+1)
      u64 hv = ((u64)(unsigned int)(t + 1) << 32) | (u64)hp;
      __hip_atomic_store(&hlay[(size_t)((t + 1) & 1) * BB * 256 + eb * 256 + lblk * 8 + jj],
                         hv, __ATOMIC_RELAXED, __HIP_MEMORY_SCOPE_AGENT);
      if (layer == 0) {
        __hip_atomic_store((unsigned int*)(ws_y + ((size_t)eb * TT + t) * HH + u0), hp,
                           __ATOMIC_RELAXED, __HIP_MEMORY_SCOPE_AGENT);
      } else {
        f32x2 o; o[0] = hA; o[1] = hB;
        *(f32x2*)(out + ((size_t)eb * TT + t) * HH + u0) = o;
      }
    }

    if (it == TT) break;

    if (layer == 0) {
      // drain ws_y stores, then publish per-step flag (guards L1's ws_y reads)
      __syncthreads();
      if (tid == 0 && active) {
        __hip_atomic_store(flags + (size_t)lblk * FLGSTRIDE, (unsigned int)(it + 1),
                           __ATOMIC_RELAXED, __HIP_MEMORY_SCOPE_AGENT);
      }
      // prefetch next x (emb gather) into LDS x-half (distinct from zlds/h-half)
      const int tn = it + 1;
      if (tn < TT) {
#pragma unroll
        for (int i = 0; i < 8; ++i) {
          int u   = tid + i * 256;
          int row = u >> 6;
          int ce  = (u & 63) * 8;
          int tok = tokens[row * TT + tn];
          const float* src = emb + (size_t)tok * HH + ce;
          f32x4 lo = *(const f32x4*)src;
          f32x4 hi = *(const f32x4*)(src + 4);
          i32x4 w;
          w[0] = pkh2(lo[0], lo[1]); w[1] = pkh2(lo[2], lo[3]);
          w[2] = pkh2(hi[0], hi[1]); w[3] = pkh2(hi[2], hi[3]);
          *(i32x4*)(&Alds[row * ALD + ce]) = w;
        }
      }
    }
  }

  if (layer == 1) {
    const size_t coff = (size_t)BB * TT * HH;
    const size_t hoff = coff + (size_t)BB * HH;
    f32x2 c2; c2[0] = cA; c2[1] = cB;
    f32x2 h2; h2[0] = hA; h2[1] = hB;
    *(f32x2*)(out + coff + (size_t)eb * HH + u0) = c2;
    *(f32x2*)(out + hoff + (size_t)eb * HH + u0) = h2;
  }
}

extern "C" void kernel_launch(void* const* d_in, const int* in_sizes, int n_in,
                              void* d_out, int out_size, void* d_ws, size_t ws_size,
                              hipStream_t stream) {
  (void)in_sizes; (void)n_in; (void)out_size; (void)ws_size;
  const int* tokens  = (const int*)d_in[0];
  const int* lengths = (const int*)d_in[1];
  const float* emb   = (const float*)d_in[2];
  const float* Wx    = (const float*)d_in[3];
  const float* Wh    = (const float*)d_in[4];
  const float* bias  = (const float*)d_in[5];

  // ws layout (~8.7 MB):
  //   [0, 4K)         flags [32] x 128B lines (L0 per-step)
  //   [4K, +256K)     htag [2 layers][2 slots][32][256] u64 (tagged h)
  //   [+256K, +8M)    ws_y [32][256][512] u16 (f16 bits)
  char* w = (char*)d_ws;
  const size_t FB = (size_t)32 * FLGSTRIDE * 4;       // 4096
  const size_t HT = (size_t)2 * 2 * BB * 256 * 8;     // 262144
  unsigned int*   flags = (unsigned int*)w;
  u64*            htag  = (u64*)(w + FB);
  unsigned short* ws_y  = (unsigned short*)(w + FB + HT);

  const int zero_words = (int)((FB + HT) / 4);
  hipLaunchKernelGGL(zero_ws_kernel, dim3((zero_words + 255) / 256), dim3(256), 0, stream,
                     (unsigned int*)d_ws, zero_words);
  hipLaunchKernelGGL(lstm_enc_kernel, dim3(NBLK), dim3(256), 0, stream,
                     tokens, lengths, emb, Wx, Wh, bias, (float*)d_out,
                     ws_y, htag, flags);
}

// Round 15
// 1867.644 us; speedup vs baseline: 2.0733x; 1.1998x over previous
//
#include <hip/hip_runtime.h>

#define BB 32
#define TT 256
#define HH 512
#define NBLK 64
#define ALD 1032   // A_lds padded row stride in elements (1024 + 8)
#define ZLD 68     // z_lds padded row stride in floats (64 + 4)
#define FLGSTRIDE 32   // u32s per flag line (128 B)

typedef float    f32x4 __attribute__((ext_vector_type(4)));
typedef float    f32x2 __attribute__((ext_vector_type(2)));
typedef int      i32x4 __attribute__((ext_vector_type(4)));
typedef _Float16 f16x8 __attribute__((ext_vector_type(8)));
typedef unsigned long long u64;

__device__ __forceinline__ unsigned short f2h(float f) {   // f32 -> f16 bits (RNE)
  union { _Float16 h; unsigned short u; } v; v.h = (_Float16)f; return v.u;
}
__device__ __forceinline__ int pkh2(float a, float b) {    // pack two f16
  return (int)((unsigned int)f2h(a) | ((unsigned int)f2h(b) << 16));
}
__device__ __forceinline__ float sigm(float x) { return 1.f / (1.f + __expf(-x)); }
__device__ __forceinline__ float tanh_(float x) {
  float ax = fabsf(x);
  float e = __expf(-2.f * ax);
  float r = (1.f - e) / (1.f + e);
  return copysignf(r, x);
}
// pipelined agent-coherent 16B load (same scope as __hip_atomic_load AGENT: sc1,
// bypasses non-coherent L1/L2) but fully pipelined — many in flight. MUST be
// followed by s_waitcnt vmcnt(0) + sched_barrier(0) before reading dst (rule-18).
__device__ __forceinline__ void ld_coh16(i32x4& dst, const void* a) {
  asm volatile("global_load_dwordx4 %0, %1, off sc1"
               : "=v"(dst) : "v"(a) : "memory");
}

__global__ void zero_ws_kernel(unsigned int* p, int nwords) {
  int i = blockIdx.x * 256 + threadIdx.x;
  if (i < nwords) p[i] = 0u;
}

// 64 persistent blocks: blk 0..31 -> layer 0, blk 32..63 -> layer 1 (one step behind).
// h recurrence synchronized by INLINE TAGS ({tag,2xf16} u64); bulk staging via
// pipelined coherent dwordx4 loads; stale tags re-polled individually (rare).
__global__ __launch_bounds__(256, 1) void lstm_enc_kernel(
    const int* __restrict__ tokens,
    const int* __restrict__ lengths,
    const float* __restrict__ emb,     // [V][512] fp32
    const float* __restrict__ Wx,      // [2][512][2048] fp32
    const float* __restrict__ Wh,      // [2][512][2048] fp32
    const float* __restrict__ bias,    // [2][2048] fp32
    float* __restrict__ out,           // y [32][256][512] ++ c [32][512] ++ h [32][512] fp32
    unsigned short* __restrict__ ws_y, // [32][256][512] layer-0 outputs (f16 bits)
    u64* __restrict__ htag,            // [2 layers][2 slots][32][256] tagged h u64
    unsigned int* __restrict__ flags)  // [32] L0 arrival flags, 128B-strided
{
  const int tid   = threadIdx.x;
  const int blk   = blockIdx.x;
  const int layer = blk >> 5;    // 0 or 1
  const int lblk  = blk & 31;    // hidden units [lblk*16, lblk*16+16)
  const int wave  = tid >> 6;    // gate index 0..3 (i,f,g,o)
  const int lane  = tid & 63;

  __shared__ unsigned short Alds[32 * ALD];   // [32 rows][1024 cols]: [x_t | h_prev] f16
  __shared__ float zlds[32 * ZLD];            // [32 rows][64 cols] fp32

  // ---- preload stacked-weight B fragments into registers (K = 1024, N = 16 per wave)
  const int nloc  = lane & 15;
  const int gcol  = wave * HH + lblk * 16 + nloc;   // column in [0,2048)
  const int krow0 = (lane >> 4) * 8;
  const float* WxL = Wx + (size_t)layer * HH * 2048;
  const float* WhL = Wh + (size_t)layer * HH * 2048;
  f16x8 breg[32];
#pragma unroll
  for (int s = 0; s < 32; ++s) {
    const float* base = (s < 16)
        ? (WxL + (size_t)(s * 32 + krow0) * 2048 + gcol)
        : (WhL + (size_t)((s - 16) * 32 + krow0) * 2048 + gcol);
    f16x8 v;
    v[0] = (_Float16)base[0 * 2048];
    v[1] = (_Float16)base[1 * 2048];
    v[2] = (_Float16)base[2 * 2048];
    v[3] = (_Float16)base[3 * 2048];
    v[4] = (_Float16)base[4 * 2048];
    v[5] = (_Float16)base[5 * 2048];
    v[6] = (_Float16)base[6 * 2048];
    v[7] = (_Float16)base[7 * 2048];
    breg[s] = v;
  }

  // ---- per-thread persistent elementwise state: one batch, two adjacent units
  const int jj  = tid & 7;             // unit-pair index 0..7
  const int eb  = tid >> 3;            // batch 0..31
  const int u0  = lblk * 16 + 2 * jj;  // global hidden units u0, u0+1
  const int len = lengths[eb];
  const float bI0 = bias[layer * 2048 +         u0], bI1 = bias[layer * 2048 +         u0 + 1];
  const float bF0 = bias[layer * 2048 +  512 +  u0], bF1 = bias[layer * 2048 +  512 +  u0 + 1];
  const float bG0 = bias[layer * 2048 + 1024 +  u0], bG1 = bias[layer * 2048 + 1024 +  u0 + 1];
  const float bO0 = bias[layer * 2048 + 1536 +  u0], bO1 = bias[layer * 2048 + 1536 +  u0 + 1];
  float cA = 0.f, hA = 0.f, cB = 0.f, hB = 0.f;

  u64* hlay = htag + (size_t)layer * 2 * BB * 256;   // own layer's tagged h, 2 slots
  unsigned int* pollL0 = flags + (size_t)(tid & 31) * FLGSTRIDE;

  // ---- prologue: layer 0 stages x(0) (emb) into LDS x-half
  if (layer == 0) {
#pragma unroll
    for (int i = 0; i < 8; ++i) {
      int u   = tid + i * 256;
      int row = u >> 6;
      int ce  = (u & 63) * 8;
      int tok = tokens[row * TT + 0];
      const float* src = emb + (size_t)tok * HH + ce;
      f32x4 lo = *(const f32x4*)src;
      f32x4 hi = *(const f32x4*)(src + 4);
      i32x4 w;
      w[0] = pkh2(lo[0], lo[1]); w[1] = pkh2(lo[2], lo[3]);
      w[2] = pkh2(hi[0], hi[1]); w[3] = pkh2(hi[2], hi[3]);
      *(i32x4*)(&Alds[row * ALD + ce]) = w;
    }
  }

  for (int it = 0;; ++it) {
    const int t = (layer == 0) ? it : (it - 1);
    const bool active = (t >= 0) && (t < TT);

    if (layer == 1 && active) {
      // ---- guard + stage x-half = ws_y[t] via pipelined coherent loads
      const unsigned int tgt = (unsigned int)(t + 1);
      if (tid < 32) {
        while (__hip_atomic_load(pollL0, __ATOMIC_RELAXED, __HIP_MEMORY_SCOPE_AGENT) < tgt) {
          __builtin_amdgcn_s_sleep(1);
        }
      }
      __syncthreads();
      i32x4 yv[8];
      int yrow[8], yco[8];
#pragma unroll
      for (int k = 0; k < 8; ++k) {
        int g = tid + k * 256;         // 16B-unit index over [32][512] f16
        yrow[k] = g >> 6;
        yco[k]  = (g & 63) * 8;
        ld_coh16(yv[k], ws_y + ((size_t)yrow[k] * TT + t) * HH + yco[k]);
      }
      asm volatile("s_waitcnt vmcnt(0)" ::: "memory");
      __builtin_amdgcn_sched_barrier(0);
#pragma unroll
      for (int k = 0; k < 8; ++k) {
        *(i32x4*)(&Alds[yrow[k] * ALD + yco[k]]) = yv[k];
      }
    }

    if (active) {
      // ---- tagged h staging: pipelined coherent loads + tag check + rare re-poll
      const u64* hsrc = hlay + (size_t)(t & 1) * BB * 256;   // [32][256] u64
      const unsigned int exp = (unsigned int)t;
      i32x4 hv[16];
#pragma unroll
      for (int k = 0; k < 16; ++k) {
        ld_coh16(hv[k], hsrc + 2 * (tid + k * 256));
      }
      asm volatile("s_waitcnt vmcnt(0)" ::: "memory");
      __builtin_amdgcn_sched_barrier(0);
      bool ok = false;
      while (!ok) {
        ok = true;
#pragma unroll
        for (int k = 0; k < 16; ++k) {
          const u64* p = hsrc + 2 * (tid + k * 256);
          if ((unsigned int)hv[k][1] != exp) {
            u64 v = __hip_atomic_load(p, __ATOMIC_RELAXED, __HIP_MEMORY_SCOPE_AGENT);
            hv[k][0] = (int)(unsigned int)v;
            hv[k][1] = (int)(unsigned int)(v >> 32);
            if ((unsigned int)(v >> 32) != exp) ok = false;
          }
          if ((unsigned int)hv[k][3] != exp) {
            u64 v = __hip_atomic_load(p + 1, __ATOMIC_RELAXED, __HIP_MEMORY_SCOPE_AGENT);
            hv[k][2] = (int)(unsigned int)v;
            hv[k][3] = (int)(unsigned int)(v >> 32);
            if ((unsigned int)(v >> 32) != exp) ok = false;
          }
        }
      }
#pragma unroll
      for (int k = 0; k < 16; ++k) {
        int g   = tid + k * 256;
        int row = g >> 7;
        int e   = 4 * (g & 127);       // element offset within h-half
        u64 d = (u64)(unsigned int)hv[k][0] | ((u64)(unsigned int)hv[k][2] << 32);
        *(u64*)(&Alds[row * ALD + 512 + e]) = d;
      }
    }
    __syncthreads();

    if (active) {
      // ---- z[32 x 16cols] for this wave's gate: 64 intrinsic MFMAs over K=1024
      f32x4 acc0 = {0.f, 0.f, 0.f, 0.f};
      f32x4 acc1 = {0.f, 0.f, 0.f, 0.f};
      const _Float16* a0p = (const _Float16*)&Alds[nloc * ALD + krow0];
      const _Float16* a1p = a0p + 16 * ALD;
#pragma unroll
      for (int s = 0; s < 32; ++s) {
        f16x8 a0 = *(const f16x8*)(a0p + s * 32);
        f16x8 a1 = *(const f16x8*)(a1p + s * 32);
        acc0 = __builtin_amdgcn_mfma_f32_16x16x32_f16(a0, breg[s], acc0, 0, 0, 0);
        acc1 = __builtin_amdgcn_mfma_f32_16x16x32_f16(a1, breg[s], acc1, 0, 0, 0);
      }
      const int zc = wave * 16 + nloc;
      const int zr = (lane >> 4) * 4;
#pragma unroll
      for (int r = 0; r < 4; ++r) {
        zlds[(zr + r) * ZLD + zc]        = acc0[r];
        zlds[(16 + zr + r) * ZLD + zc]   = acc1[r];
      }
    }
    __syncthreads();   // A-tile dead from here; zlds valid

    if (active) {
      float zi0 = zlds[eb * ZLD +      2 * jj] + bI0, zi1 = zlds[eb * ZLD +      2 * jj + 1] + bI1;
      float zf0 = zlds[eb * ZLD + 16 + 2 * jj] + bF0, zf1 = zlds[eb * ZLD + 16 + 2 * jj + 1] + bF1;
      float zg0 = zlds[eb * ZLD + 32 + 2 * jj] + bG0, zg1 = zlds[eb * ZLD + 32 + 2 * jj + 1] + bG1;
      float zo0 = zlds[eb * ZLD + 48 + 2 * jj] + bO0, zo1 = zlds[eb * ZLD + 48 + 2 * jj + 1] + bO1;
      float ncA = sigm(zf0) * cA + sigm(zi0) * tanh_(zg0);
      float nhA = sigm(zo0) * tanh_(ncA);
      float ncB = sigm(zf1) * cB + sigm(zi1) * tanh_(zg1);
      float nhB = sigm(zo1) * tanh_(ncB);
      if (t < len) { cA = ncA; hA = nhA; cB = ncB; hB = nhB; }
      unsigned int hp = (unsigned int)f2h(hA) | ((unsigned int)f2h(hB) << 16);
      // publish tagged h for step t (consumed at t+1 expecting tag t+1)
      u64 hv2 = ((u64)(unsigned int)(t + 1) << 32) | (u64)hp;
      __hip_atomic_store(&hlay[(size_t)((t + 1) & 1) * BB * 256 + eb * 256 + lblk * 8 + jj],
                         hv2, __ATOMIC_RELAXED, __HIP_MEMORY_SCOPE_AGENT);
      if (layer == 0) {
        __hip_atomic_store((unsigned int*)(ws_y + ((size_t)eb * TT + t) * HH + u0), hp,
                           __ATOMIC_RELAXED, __HIP_MEMORY_SCOPE_AGENT);
      } else {
        f32x2 o; o[0] = hA; o[1] = hB;
        *(f32x2*)(out + ((size_t)eb * TT + t) * HH + u0) = o;
      }
    }

    if (it == TT) break;

    if (layer == 0) {
      // drain ws_y stores, then publish per-step flag (guards L1's ws_y reads)
      __syncthreads();
      if (tid == 0 && active) {
        __hip_atomic_store(flags + (size_t)lblk * FLGSTRIDE, (unsigned int)(it + 1),
                           __ATOMIC_RELAXED, __HIP_MEMORY_SCOPE_AGENT);
      }
      // prefetch next x (emb gather) into LDS x-half (distinct from zlds/h-half)
      const int tn = it + 1;
      if (tn < TT) {
#pragma unroll
        for (int i = 0; i < 8; ++i) {
          int u   = tid + i * 256;
          int row = u >> 6;
          int ce  = (u & 63) * 8;
          int tok = tokens[row * TT + tn];
          const float* src = emb + (size_t)tok * HH + ce;
          f32x4 lo = *(const f32x4*)src;
          f32x4 hi = *(const f32x4*)(src + 4);
          i32x4 w;
          w[0] = pkh2(lo[0], lo[1]); w[1] = pkh2(lo[2], lo[3]);
          w[2] = pkh2(hi[0], hi[1]); w[3] = pkh2(hi[2], hi[3]);
          *(i32x4*)(&Alds[row * ALD + ce]) = w;
        }
      }
    }
  }

  if (layer == 1) {
    const size_t coff = (size_t)BB * TT * HH;
    const size_t hoff = coff + (size_t)BB * HH;
    f32x2 c2; c2[0] = cA; c2[1] = cB;
    f32x2 h2; h2[0] = hA; h2[1] = hB;
    *(f32x2*)(out + coff + (size_t)eb * HH + u0) = c2;
    *(f32x2*)(out + hoff + (size_t)eb * HH + u0) = h2;
  }
}

extern "C" void kernel_launch(void* const* d_in, const int* in_sizes, int n_in,
                              void* d_out, int out_size, void* d_ws, size_t ws_size,
                              hipStream_t stream) {
  (void)in_sizes; (void)n_in; (void)out_size; (void)ws_size;
  const int* tokens  = (const int*)d_in[0];
  const int* lengths = (const int*)d_in[1];
  const float* emb   = (const float*)d_in[2];
  const float* Wx    = (const float*)d_in[3];
  const float* Wh    = (const float*)d_in[4];
  const float* bias  = (const float*)d_in[5];

  // ws layout (~8.7 MB):
  //   [0, 4K)         flags [32] x 128B lines (L0 per-step)
  //   [4K, +256K)     htag [2 layers][2 slots][32][256] u64 (tagged h)
  //   [+256K, +8M)    ws_y [32][256][512] u16 (f16 bits)
  char* w = (char*)d_ws;
  const size_t FB = (size_t)32 * FLGSTRIDE * 4;       // 4096
  const size_t HT = (size_t)2 * 2 * BB * 256 * 8;     // 262144
  unsigned int*   flags = (unsigned int*)w;
  u64*            htag  = (u64*)(w + FB);
  unsigned short* ws_y  = (unsigned short*)(w + FB + HT);

  const int zero_words = (int)((FB + HT) / 4);
  hipLaunchKernelGGL(zero_ws_kernel, dim3((zero_words + 255) / 256), dim3(256), 0, stream,
                     (unsigned int*)d_ws, zero_words);
  hipLaunchKernelGGL(lstm_enc_kernel, dim3(NBLK), dim3(256), 0, stream,
                     tokens, lengths, emb, Wx, Wh, bias, (float*)d_out,
                     ws_y, htag, flags);
}

// Round 16
// 1654.873 us; speedup vs baseline: 2.3398x; 1.1286x over previous
//
#include <hip/hip_runtime.h>

#define BB 32
#define TT 256
#define HH 512
#define NBLK 64
#define ALD 1032   // A_lds padded row stride in elements (1024 + 8)
#define ZLD 68     // z_lds padded row stride in floats (64 + 4)
#define FLGSTRIDE 32   // u32s per flag line (128 B)

typedef float    f32x4 __attribute__((ext_vector_type(4)));
typedef float    f32x2 __attribute__((ext_vector_type(2)));
typedef int      i32x4 __attribute__((ext_vector_type(4)));
typedef _Float16 f16x8 __attribute__((ext_vector_type(8)));
typedef unsigned long long u64;

__device__ __forceinline__ unsigned short f2h(float f) {   // f32 -> f16 bits (RNE)
  union { _Float16 h; unsigned short u; } v; v.h = (_Float16)f; return v.u;
}
__device__ __forceinline__ int pkh2(float a, float b) {    // pack two f16
  return (int)((unsigned int)f2h(a) | ((unsigned int)f2h(b) << 16));
}
__device__ __forceinline__ float sigm(float x) { return 1.f / (1.f + __expf(-x)); }
__device__ __forceinline__ float tanh_(float x) {
  float ax = fabsf(x);
  float e = __expf(-2.f * ax);
  float r = (1.f - e) / (1.f + e);
  return copysignf(r, x);
}
// pipelined agent-coherent 16B load (sc1: bypasses non-coherent L1/L2, same scope
// as __hip_atomic_load AGENT) but fully pipelined — many in flight. MUST be
// followed by s_waitcnt vmcnt(0) + sched_barrier(0) before reading dst (rule-18).
__device__ __forceinline__ void ld_coh16(i32x4& dst, const void* a) {
  asm volatile("global_load_dwordx4 %0, %1, off sc1"
               : "=v"(dst) : "v"(a) : "memory");
}

__global__ void zero_ws_kernel(unsigned int* p, int nwords) {
  int i = blockIdx.x * 256 + threadIdx.x;
  if (i < nwords) p[i] = 0u;
}

// 64 persistent blocks: blk 0..31 -> layer 0, blk 32..63 -> layer 1 (one step behind).
// h recurrence synchronized by INLINE TAGS ({tag,2xf16} u64); staging AND retry are
// bulk pipelined coherent loads (no serialized atomic re-poll anywhere).
__global__ __launch_bounds__(256, 1) void lstm_enc_kernel(
    const int* __restrict__ tokens,
    const int* __restrict__ lengths,
    const float* __restrict__ emb,     // [V][512] fp32
    const float* __restrict__ Wx,      // [2][512][2048] fp32
    const float* __restrict__ Wh,      // [2][512][2048] fp32
    const float* __restrict__ bias,    // [2][2048] fp32
    float* __restrict__ out,           // y [32][256][512] ++ c [32][512] ++ h [32][512] fp32
    unsigned short* __restrict__ ws_y, // [32][256][512] layer-0 outputs (f16 bits)
    u64* __restrict__ htag,            // [2 layers][2 slots][32][256] tagged h u64
    unsigned int* __restrict__ flags)  // [32] L0 arrival flags, 128B-strided
{
  const int tid   = threadIdx.x;
  const int blk   = blockIdx.x;
  const int layer = blk >> 5;    // 0 or 1
  const int lblk  = blk & 31;    // hidden units [lblk*16, lblk*16+16)
  const int wave  = tid >> 6;    // gate index 0..3 (i,f,g,o)
  const int lane  = tid & 63;

  __shared__ unsigned short Alds[32 * ALD];   // [32 rows][1024 cols]: [x_t | h_prev] f16
  __shared__ float zlds[32 * ZLD];            // [32 rows][64 cols] fp32

  // ---- preload stacked-weight B fragments into registers (K = 1024, N = 16 per wave)
  const int nloc  = lane & 15;
  const int gcol  = wave * HH + lblk * 16 + nloc;   // column in [0,2048)
  const int krow0 = (lane >> 4) * 8;
  const float* WxL = Wx + (size_t)layer * HH * 2048;
  const float* WhL = Wh + (size_t)layer * HH * 2048;
  f16x8 breg[32];
#pragma unroll
  for (int s = 0; s < 32; ++s) {
    const float* base = (s < 16)
        ? (WxL + (size_t)(s * 32 + krow0) * 2048 + gcol)
        : (WhL + (size_t)((s - 16) * 32 + krow0) * 2048 + gcol);
    f16x8 v;
    v[0] = (_Float16)base[0 * 2048];
    v[1] = (_Float16)base[1 * 2048];
    v[2] = (_Float16)base[2 * 2048];
    v[3] = (_Float16)base[3 * 2048];
    v[4] = (_Float16)base[4 * 2048];
    v[5] = (_Float16)base[5 * 2048];
    v[6] = (_Float16)base[6 * 2048];
    v[7] = (_Float16)base[7 * 2048];
    breg[s] = v;
  }

  // ---- per-thread persistent elementwise state: one batch, two adjacent units
  const int jj  = tid & 7;             // unit-pair index 0..7
  const int eb  = tid >> 3;            // batch 0..31
  const int u0  = lblk * 16 + 2 * jj;  // global hidden units u0, u0+1
  const int len = lengths[eb];
  const float bI0 = bias[layer * 2048 +         u0], bI1 = bias[layer * 2048 +         u0 + 1];
  const float bF0 = bias[layer * 2048 +  512 +  u0], bF1 = bias[layer * 2048 +  512 +  u0 + 1];
  const float bG0 = bias[layer * 2048 + 1024 +  u0], bG1 = bias[layer * 2048 + 1024 +  u0 + 1];
  const float bO0 = bias[layer * 2048 + 1536 +  u0], bO1 = bias[layer * 2048 + 1536 +  u0 + 1];
  float cA = 0.f, hA = 0.f, cB = 0.f, hB = 0.f;

  u64* hlay = htag + (size_t)layer * 2 * BB * 256;   // own layer's tagged h, 2 slots
  unsigned int* pollL0 = flags + (size_t)(tid & 31) * FLGSTRIDE;

  // ---- prologue: layer 0 stages x(0) (emb) into LDS x-half
  if (layer == 0) {
#pragma unroll
    for (int i = 0; i < 8; ++i) {
      int u   = tid + i * 256;
      int row = u >> 6;
      int ce  = (u & 63) * 8;
      int tok = tokens[row * TT + 0];
      const float* src = emb + (size_t)tok * HH + ce;
      f32x4 lo = *(const f32x4*)src;
      f32x4 hi = *(const f32x4*)(src + 4);
      i32x4 w;
      w[0] = pkh2(lo[0], lo[1]); w[1] = pkh2(lo[2], lo[3]);
      w[2] = pkh2(hi[0], hi[1]); w[3] = pkh2(hi[2], hi[3]);
      *(i32x4*)(&Alds[row * ALD + ce]) = w;
    }
  }

  for (int it = 0;; ++it) {
    const int t = (layer == 0) ? it : (it - 1);
    const bool active = (t >= 0) && (t < TT);

    if (layer == 1 && active) {
      // ---- guard + stage x-half = ws_y[t] via pipelined coherent loads
      const unsigned int tgt = (unsigned int)(t + 1);
      if (tid < 32) {
        while (__hip_atomic_load(pollL0, __ATOMIC_RELAXED, __HIP_MEMORY_SCOPE_AGENT) < tgt) {
          __builtin_amdgcn_s_sleep(1);
        }
      }
      __syncthreads();
      i32x4 yv[8];
      int yrow[8], yco[8];
#pragma unroll
      for (int k = 0; k < 8; ++k) {
        int g = tid + k * 256;         // 16B-unit index over [32][512] f16
        yrow[k] = g >> 6;
        yco[k]  = (g & 63) * 8;
        ld_coh16(yv[k], ws_y + ((size_t)yrow[k] * TT + t) * HH + yco[k]);
      }
      asm volatile("s_waitcnt vmcnt(0)" ::: "memory");
      __builtin_amdgcn_sched_barrier(0);
#pragma unroll
      for (int k = 0; k < 8; ++k) {
        *(i32x4*)(&Alds[yrow[k] * ALD + yco[k]]) = yv[k];
      }
    }

    if (active) {
      // ---- tagged h staging: bulk pipelined rounds until ALL tags == t
      const u64* hsrc = hlay + (size_t)(t & 1) * BB * 256;   // [32][256] u64
      const unsigned int exp = (unsigned int)t;
      i32x4 hv[16];
      bool ok = false;
      while (!ok) {
#pragma unroll
        for (int k = 0; k < 16; ++k) {
          ld_coh16(hv[k], hsrc + 2 * (tid + k * 256));
        }
        asm volatile("s_waitcnt vmcnt(0)" ::: "memory");
        __builtin_amdgcn_sched_barrier(0);
        ok = true;
#pragma unroll
        for (int k = 0; k < 16; ++k) {
          if ((unsigned int)hv[k][1] != exp) ok = false;
          if ((unsigned int)hv[k][3] != exp) ok = false;
        }
      }
#pragma unroll
      for (int k = 0; k < 16; ++k) {
        int g   = tid + k * 256;
        int row = g >> 7;
        int e   = 4 * (g & 127);       // element offset within h-half
        u64 d = (u64)(unsigned int)hv[k][0] | ((u64)(unsigned int)hv[k][2] << 32);
        *(u64*)(&Alds[row * ALD + 512 + e]) = d;
      }
    }
    __syncthreads();

    if (active) {
      // ---- z[32 x 16cols] for this wave's gate: 64 intrinsic MFMAs over K=1024
      f32x4 acc0 = {0.f, 0.f, 0.f, 0.f};
      f32x4 acc1 = {0.f, 0.f, 0.f, 0.f};
      const _Float16* a0p = (const _Float16*)&Alds[nloc * ALD + krow0];
      const _Float16* a1p = a0p + 16 * ALD;
#pragma unroll
      for (int s = 0; s < 32; ++s) {
        f16x8 a0 = *(const f16x8*)(a0p + s * 32);
        f16x8 a1 = *(const f16x8*)(a1p + s * 32);
        acc0 = __builtin_amdgcn_mfma_f32_16x16x32_f16(a0, breg[s], acc0, 0, 0, 0);
        acc1 = __builtin_amdgcn_mfma_f32_16x16x32_f16(a1, breg[s], acc1, 0, 0, 0);
      }
      const int zc = wave * 16 + nloc;
      const int zr = (lane >> 4) * 4;
#pragma unroll
      for (int r = 0; r < 4; ++r) {
        zlds[(zr + r) * ZLD + zc]        = acc0[r];
        zlds[(16 + zr + r) * ZLD + zc]   = acc1[r];
      }
    }
    __syncthreads();   // A-tile dead from here; zlds valid

    if (active) {
      float zi0 = zlds[eb * ZLD +      2 * jj] + bI0, zi1 = zlds[eb * ZLD +      2 * jj + 1] + bI1;
      float zf0 = zlds[eb * ZLD + 16 + 2 * jj] + bF0, zf1 = zlds[eb * ZLD + 16 + 2 * jj + 1] + bF1;
      float zg0 = zlds[eb * ZLD + 32 + 2 * jj] + bG0, zg1 = zlds[eb * ZLD + 32 + 2 * jj + 1] + bG1;
      float zo0 = zlds[eb * ZLD + 48 + 2 * jj] + bO0, zo1 = zlds[eb * ZLD + 48 + 2 * jj + 1] + bO1;
      float ncA = sigm(zf0) * cA + sigm(zi0) * tanh_(zg0);
      float nhA = sigm(zo0) * tanh_(ncA);
      float ncB = sigm(zf1) * cB + sigm(zi1) * tanh_(zg1);
      float nhB = sigm(zo1) * tanh_(ncB);
      if (t < len) { cA = ncA; hA = nhA; cB = ncB; hB = nhB; }
      unsigned int hp = (unsigned int)f2h(hA) | ((unsigned int)f2h(hB) << 16);
      // publish tagged h for step t (consumed at t+1 expecting tag t+1)
      u64 hv2 = ((u64)(unsigned int)(t + 1) << 32) | (u64)hp;
      __hip_atomic_store(&hlay[(size_t)((t + 1) & 1) * BB * 256 + eb * 256 + lblk * 8 + jj],
                         hv2, __ATOMIC_RELAXED, __HIP_MEMORY_SCOPE_AGENT);
      if (layer == 0) {
        __hip_atomic_store((unsigned int*)(ws_y + ((size_t)eb * TT + t) * HH + u0), hp,
                           __ATOMIC_RELAXED, __HIP_MEMORY_SCOPE_AGENT);
      } else {
        f32x2 o; o[0] = hA; o[1] = hB;
        *(f32x2*)(out + ((size_t)eb * TT + t) * HH + u0) = o;
      }
    }

    if (it == TT) break;

    if (layer == 0) {
      // drain ws_y stores, then publish per-step flag (guards L1's ws_y reads)
      __syncthreads();
      if (tid == 0 && active) {
        __hip_atomic_store(flags + (size_t)lblk * FLGSTRIDE, (unsigned int)(it + 1),
                           __ATOMIC_RELAXED, __HIP_MEMORY_SCOPE_AGENT);
      }
      // prefetch next x (emb gather) into LDS x-half (distinct from zlds/h-half)
      const int tn = it + 1;
      if (tn < TT) {
#pragma unroll
        for (int i = 0; i < 8; ++i) {
          int u   = tid + i * 256;
          int row = u >> 6;
          int ce  = (u & 63) * 8;
          int tok = tokens[row * TT + tn];
          const float* src = emb + (size_t)tok * HH + ce;
          f32x4 lo = *(const f32x4*)src;
          f32x4 hi = *(const f32x4*)(src + 4);
          i32x4 w;
          w[0] = pkh2(lo[0], lo[1]); w[1] = pkh2(lo[2], lo[3]);
          w[2] = pkh2(hi[0], hi[1]); w[3] = pkh2(hi[2], hi[3]);
          *(i32x4*)(&Alds[row * ALD + ce]) = w;
        }
      }
    }
  }

  if (layer == 1) {
    const size_t coff = (size_t)BB * TT * HH;
    const size_t hoff = coff + (size_t)BB * HH;
    f32x2 c2; c2[0] = cA; c2[1] = cB;
    f32x2 h2; h2[0] = hA; h2[1] = hB;
    *(f32x2*)(out + coff + (size_t)eb * HH + u0) = c2;
    *(f32x2*)(out + hoff + (size_t)eb * HH + u0) = h2;
  }
}

extern "C" void kernel_launch(void* const* d_in, const int* in_sizes, int n_in,
                              void* d_out, int out_size, void* d_ws, size_t ws_size,
                              hipStream_t stream) {
  (void)in_sizes; (void)n_in; (void)out_size; (void)ws_size;
  const int* tokens  = (const int*)d_in[0];
  const int* lengths = (const int*)d_in[1];
  const float* emb   = (const float*)d_in[2];
  const float* Wx    = (const float*)d_in[3];
  const float* Wh    = (const float*)d_in[4];
  const float* bias  = (const float*)d_in[5];

  // ws layout (~8.7 MB):
  //   [0, 4K)         flags [32] x 128B lines (L0 per-step)
  //   [4K, +256K)     htag [2 layers][2 slots][32][256] u64 (tagged h)
  //   [+256K, +8M)    ws_y [32][256][512] u16 (f16 bits)
  char* w = (char*)d_ws;
  const size_t FB = (size_t)32 * FLGSTRIDE * 4;       // 4096
  const size_t HT = (size_t)2 * 2 * BB * 256 * 8;     // 262144
  unsigned int*   flags = (unsigned int*)w;
  u64*            htag  = (u64*)(w + FB);
  unsigned short* ws_y  = (unsigned short*)(w + FB + HT);

  const int zero_words = (int)((FB + HT) / 4);
  hipLaunchKernelGGL(zero_ws_kernel, dim3((zero_words + 255) / 256), dim3(256), 0, stream,
                     (unsigned int*)d_ws, zero_words);
  hipLaunchKernelGGL(lstm_enc_kernel, dim3(NBLK), dim3(256), 0, stream,
                     tokens, lengths, emb, Wx, Wh, bias, (float*)d_out,
                     ws_y, htag, flags);
}

// Round 17
// 1596.927 us; speedup vs baseline: 2.4247x; 1.0363x over previous
//
#include <hip/hip_runtime.h>

#define BB 32
#define TT 256
#define HH 512
#define ALD 1032   // A_lds padded row stride in elements (1024 + 8)
#define ZLD 68     // z_lds padded row stride in floats (64 + 4)
#define FLGSTRIDE 32   // u32s per flag line (128 B)
#define GRIDN 512

typedef float    f32x4 __attribute__((ext_vector_type(4)));
typedef float    f32x2 __attribute__((ext_vector_type(2)));
typedef int      i32x4 __attribute__((ext_vector_type(4)));
typedef _Float16 f16x8 __attribute__((ext_vector_type(8)));
typedef unsigned long long u64;

__device__ __forceinline__ unsigned short f2h(float f) {
  union { _Float16 h; unsigned short u; } v; v.h = (_Float16)f; return v.u;
}
__device__ __forceinline__ int pkh2(float a, float b) {
  return (int)((unsigned int)f2h(a) | ((unsigned int)f2h(b) << 16));
}
__device__ __forceinline__ float sigm(float x) { return 1.f / (1.f + __expf(-x)); }
__device__ __forceinline__ float tanh_(float x) {
  float ax = fabsf(x);
  float e = __expf(-2.f * ax);
  float r = (1.f - e) / (1.f + e);
  return copysignf(r, x);
}
// fabric-coherent pipelined 16B load (sc1: bypasses L1+L2, device scope)
__device__ __forceinline__ void ld_coh16(i32x4& dst, const void* a) {
  asm volatile("global_load_dwordx4 %0, %1, off sc1" : "=v"(dst) : "v"(a) : "memory");
}
// XCD-local pipelined 16B load (sc0: bypasses L1, reads own-XCD shared L2)
__device__ __forceinline__ void ld_l2_16(i32x4& dst, const void* a) {
  asm volatile("global_load_dwordx4 %0, %1, off sc0" : "=v"(dst) : "v"(a) : "memory");
}
// XCD-local 8B store (plain: write-through L1 into own-XCD L2)
__device__ __forceinline__ void st_l2_8(void* a, u64 v) {
  asm volatile("global_store_dwordx2 %0, %1, off" :: "v"(a), "v"(v) : "memory");
}

__global__ void zero_ws_kernel(unsigned int* p, int nwords) {
  int i = blockIdx.x * 256 + threadIdx.x;
  if (i < nwords) p[i] = 0u;
}

// 512 blocks launched; 64 claim roles (L0 on home XCD, L1 on home+1), rest exit.
// h exchanged via own-XCD L2 (sc0/plain, tag-validated) with sticky sc1 fallback.
__global__ __launch_bounds__(256, 1) void lstm_enc_kernel(
    const int* __restrict__ tokens,
    const int* __restrict__ lengths,
    const float* __restrict__ emb,     // [V][512] fp32
    const float* __restrict__ Wx,      // [2][512][2048] fp32
    const float* __restrict__ Wh,      // [2][512][2048] fp32
    const float* __restrict__ bias,    // [2][2048] fp32
    float* __restrict__ out,           // y ++ c ++ h fp32
    unsigned short* __restrict__ ws_y, // [32][256][512] f16 bits
    u64* __restrict__ htagL,           // [2][2][32][256] tagged h (XCD-local copy)
    u64* __restrict__ htagG,           // [2][2][32][256] tagged h (fabric copy)
    unsigned int* __restrict__ flags,  // [32] L0 arrival flags, 128B-strided
    unsigned int* __restrict__ ctl)    // [0]=home|0x100, [32]=ctrA, [64]=ctrB, [96]=claimed
{
  const int tid = threadIdx.x;

  // ---- role claim: L0 roles on home XCD, L1 on home+1; overflow after capped spin
  __shared__ int sRole;
  if (tid == 0) {
    unsigned int xcc;
    asm volatile("s_getreg_b32 %0, hwreg(HW_REG_XCC_ID)" : "=s"(xcc));
    xcc &= 7u;
    if (blockIdx.x == 0) {
      __hip_atomic_store(&ctl[0], 0x100u | xcc, __ATOMIC_RELAXED, __HIP_MEMORY_SCOPE_AGENT);
    }
    unsigned int hw;
    while ((((hw = __hip_atomic_load(&ctl[0], __ATOMIC_RELAXED, __HIP_MEMORY_SCOPE_AGENT))) & 0x100u) == 0u) {
      __builtin_amdgcn_s_sleep(1);
    }
    const unsigned int home0 = hw & 7u, home1 = (home0 + 1u) & 7u;
    int role = -1;
    if (xcc == home0) {
      unsigned int i = __hip_atomic_fetch_add(&ctl[32], 1u, __ATOMIC_RELAXED, __HIP_MEMORY_SCOPE_AGENT);
      if (i < 32u) role = (int)i;
    } else if (xcc == home1) {
      unsigned int i = __hip_atomic_fetch_add(&ctl[64], 1u, __ATOMIC_RELAXED, __HIP_MEMORY_SCOPE_AGENT);
      if (i < 32u) role = 32 + (int)i;
    }
    if (role < 0) {
      // capped spin; if roles still unfilled (degraded topology), claim anyway
      unsigned int cl = 0; int spins = 0;
      while ((cl = __hip_atomic_load(&ctl[96], __ATOMIC_RELAXED, __HIP_MEMORY_SCOPE_AGENT)) < 64u
             && spins < 20000) { __builtin_amdgcn_s_sleep(2); ++spins; }
      if (cl < 64u) {
        unsigned int i = __hip_atomic_fetch_add(&ctl[32], 1u, __ATOMIC_RELAXED, __HIP_MEMORY_SCOPE_AGENT);
        if (i < 32u) role = (int)i;
        else {
          unsigned int j = __hip_atomic_fetch_add(&ctl[64], 1u, __ATOMIC_RELAXED, __HIP_MEMORY_SCOPE_AGENT);
          if (j < 32u) role = 32 + (int)j;
        }
      }
    }
    if (role >= 0)
      __hip_atomic_fetch_add(&ctl[96], 1u, __ATOMIC_RELAXED, __HIP_MEMORY_SCOPE_AGENT);
    sRole = role;
  }
  __syncthreads();
  const int role = sRole;
  if (role < 0) return;
  const int layer = role >> 5;
  const int lblk  = role & 31;
  const int wave  = tid >> 6;
  const int lane  = tid & 63;

  __shared__ unsigned short Alds[32 * ALD];
  __shared__ float zlds[32 * ZLD];

  // ---- preload stacked-weight B fragments (K = 1024, N = 16 per wave)
  const int nloc  = lane & 15;
  const int gcol  = wave * HH + lblk * 16 + nloc;
  const int krow0 = (lane >> 4) * 8;
  const float* WxL = Wx + (size_t)layer * HH * 2048;
  const float* WhL = Wh + (size_t)layer * HH * 2048;
  f16x8 breg[32];
#pragma unroll
  for (int s = 0; s < 32; ++s) {
    const float* base = (s < 16)
        ? (WxL + (size_t)(s * 32 + krow0) * 2048 + gcol)
        : (WhL + (size_t)((s - 16) * 32 + krow0) * 2048 + gcol);
    f16x8 v;
    v[0] = (_Float16)base[0 * 2048];
    v[1] = (_Float16)base[1 * 2048];
    v[2] = (_Float16)base[2 * 2048];
    v[3] = (_Float16)base[3 * 2048];
    v[4] = (_Float16)base[4 * 2048];
    v[5] = (_Float16)base[5 * 2048];
    v[6] = (_Float16)base[6 * 2048];
    v[7] = (_Float16)base[7 * 2048];
    breg[s] = v;
  }

  // ---- per-thread elementwise state: one batch, two adjacent units
  const int jj  = tid & 7;
  const int eb  = tid >> 3;
  const int u0  = lblk * 16 + 2 * jj;
  const int len = lengths[eb];
  const float bI0 = bias[layer * 2048 +         u0], bI1 = bias[layer * 2048 +         u0 + 1];
  const float bF0 = bias[layer * 2048 +  512 +  u0], bF1 = bias[layer * 2048 +  512 +  u0 + 1];
  const float bG0 = bias[layer * 2048 + 1024 +  u0], bG1 = bias[layer * 2048 + 1024 +  u0 + 1];
  const float bO0 = bias[layer * 2048 + 1536 +  u0], bO1 = bias[layer * 2048 + 1536 +  u0 + 1];
  float cA = 0.f, hA = 0.f, cB = 0.f, hB = 0.f;

  u64* hlayL = htagL + (size_t)layer * 2 * BB * 256;
  u64* hlayG = htagG + (size_t)layer * 2 * BB * 256;
  unsigned int* pollL0 = flags + (size_t)(tid & 31) * FLGSTRIDE;
  bool useG = false;   // sticky fallback to fabric copy

  // ---- prologue: layer 0 stages x(0) into LDS x-half
  if (layer == 0) {
#pragma unroll
    for (int i = 0; i < 8; ++i) {
      int u   = tid + i * 256;
      int row = u >> 6;
      int ce  = (u & 63) * 8;
      int tok = tokens[row * TT + 0];
      const float* src = emb + (size_t)tok * HH + ce;
      f32x4 lo = *(const f32x4*)src;
      f32x4 hi = *(const f32x4*)(src + 4);
      i32x4 w;
      w[0] = pkh2(lo[0], lo[1]); w[1] = pkh2(lo[2], lo[3]);
      w[2] = pkh2(hi[0], hi[1]); w[3] = pkh2(hi[2], hi[3]);
      *(i32x4*)(&Alds[row * ALD + ce]) = w;
    }
  }

  for (int it = 0;; ++it) {
    const int t = (layer == 0) ? it : (it - 1);
    const bool active = (t >= 0) && (t < TT);

    if (layer == 1 && active) {
      const unsigned int tgt = (unsigned int)(t + 1);
      if (tid < 32) {
        while (__hip_atomic_load(pollL0, __ATOMIC_RELAXED, __HIP_MEMORY_SCOPE_AGENT) < tgt) {
          __builtin_amdgcn_s_sleep(1);
        }
      }
      __syncthreads();
      i32x4 yv[8];
      int yrow[8], yco[8];
#pragma unroll
      for (int k = 0; k < 8; ++k) {
        int g = tid + k * 256;
        yrow[k] = g >> 6;
        yco[k]  = (g & 63) * 8;
        ld_coh16(yv[k], ws_y + ((size_t)yrow[k] * TT + t) * HH + yco[k]);
      }
      asm volatile("s_waitcnt vmcnt(0)" ::: "memory");
      __builtin_amdgcn_sched_barrier(0);
#pragma unroll
      for (int k = 0; k < 8; ++k) {
        *(i32x4*)(&Alds[yrow[k] * ALD + yco[k]]) = yv[k];
      }
    }

    if (active) {
      // ---- tagged h staging: bulk rounds on local L2 copy; sticky sc1 fallback
      const u64* srcL = hlayL + (size_t)(t & 1) * BB * 256;
      const u64* srcG = hlayG + (size_t)(t & 1) * BB * 256;
      const unsigned int exp = (unsigned int)t;
      i32x4 hv[16];
      int rounds = 0;
      bool ok = false;
      while (!ok) {
        if (useG) {
#pragma unroll
          for (int k = 0; k < 16; ++k) ld_coh16(hv[k], srcG + 2 * (tid + k * 256));
        } else {
#pragma unroll
          for (int k = 0; k < 16; ++k) ld_l2_16(hv[k], srcL + 2 * (tid + k * 256));
        }
        asm volatile("s_waitcnt vmcnt(0)" ::: "memory");
        __builtin_amdgcn_sched_barrier(0);
        ok = true;
#pragma unroll
        for (int k = 0; k < 16; ++k) {
          if ((unsigned int)hv[k][1] != exp) ok = false;
          if ((unsigned int)hv[k][3] != exp) ok = false;
        }
        if (!ok && ++rounds > 48) useG = true;
      }
#pragma unroll
      for (int k = 0; k < 16; ++k) {
        int g   = tid + k * 256;
        int row = g >> 7;
        int e   = 4 * (g & 127);
        u64 d = (u64)(unsigned int)hv[k][0] | ((u64)(unsigned int)hv[k][2] << 32);
        *(u64*)(&Alds[row * ALD + 512 + e]) = d;
      }
    }
    __syncthreads();

    if (active) {
      f32x4 acc0 = {0.f, 0.f, 0.f, 0.f};
      f32x4 acc1 = {0.f, 0.f, 0.f, 0.f};
      const _Float16* a0p = (const _Float16*)&Alds[nloc * ALD + krow0];
      const _Float16* a1p = a0p + 16 * ALD;
#pragma unroll
      for (int s = 0; s < 32; ++s) {
        f16x8 a0 = *(const f16x8*)(a0p + s * 32);
        f16x8 a1 = *(const f16x8*)(a1p + s * 32);
        acc0 = __builtin_amdgcn_mfma_f32_16x16x32_f16(a0, breg[s], acc0, 0, 0, 0);
        acc1 = __builtin_amdgcn_mfma_f32_16x16x32_f16(a1, breg[s], acc1, 0, 0, 0);
      }
      const int zc = wave * 16 + nloc;
      const int zr = (lane >> 4) * 4;
#pragma unroll
      for (int r = 0; r < 4; ++r) {
        zlds[(zr + r) * ZLD + zc]        = acc0[r];
        zlds[(16 + zr + r) * ZLD + zc]   = acc1[r];
      }
    }
    __syncthreads();

    if (active) {
      float zi0 = zlds[eb * ZLD +      2 * jj] + bI0, zi1 = zlds[eb * ZLD +      2 * jj + 1] + bI1;
      float zf0 = zlds[eb * ZLD + 16 + 2 * jj] + bF0, zf1 = zlds[eb * ZLD + 16 + 2 * jj + 1] + bF1;
      float zg0 = zlds[eb * ZLD + 32 + 2 * jj] + bG0, zg1 = zlds[eb * ZLD + 32 + 2 * jj + 1] + bG1;
      float zo0 = zlds[eb * ZLD + 48 + 2 * jj] + bO0, zo1 = zlds[eb * ZLD + 48 + 2 * jj + 1] + bO1;
      float ncA = sigm(zf0) * cA + sigm(zi0) * tanh_(zg0);
      float nhA = sigm(zo0) * tanh_(ncA);
      float ncB = sigm(zf1) * cB + sigm(zi1) * tanh_(zg1);
      float nhB = sigm(zo1) * tanh_(ncB);
      if (t < len) { cA = ncA; hA = nhA; cB = ncB; hB = nhB; }
      unsigned int hp = (unsigned int)f2h(hA) | ((unsigned int)f2h(hB) << 16);
      u64 hv2 = ((u64)(unsigned int)(t + 1) << 32) | (u64)hp;
      const size_t hoff = (size_t)((t + 1) & 1) * BB * 256 + eb * 256 + lblk * 8 + jj;
      st_l2_8(&hlayL[hoff], hv2);   // XCD-local copy (fast path)
      __hip_atomic_store(&hlayG[hoff], hv2, __ATOMIC_RELAXED, __HIP_MEMORY_SCOPE_AGENT);
      if (layer == 0) {
        __hip_atomic_store((unsigned int*)(ws_y + ((size_t)eb * TT + t) * HH + u0), hp,
                           __ATOMIC_RELAXED, __HIP_MEMORY_SCOPE_AGENT);
      } else {
        f32x2 o; o[0] = hA; o[1] = hB;
        *(f32x2*)(out + ((size_t)eb * TT + t) * HH + u0) = o;
      }
    }

    if (it == TT) break;

    if (layer == 0) {
      __syncthreads();   // drains vmcnt: ws_y + h stores complete before flag
      if (tid == 0 && active) {
        __hip_atomic_store(flags + (size_t)lblk * FLGSTRIDE, (unsigned int)(it + 1),
                           __ATOMIC_RELAXED, __HIP_MEMORY_SCOPE_AGENT);
      }
      const int tn = it + 1;
      if (tn < TT) {
#pragma unroll
        for (int i = 0; i < 8; ++i) {
          int u   = tid + i * 256;
          int row = u >> 6;
          int ce  = (u & 63) * 8;
          int tok = tokens[row * TT + tn];
          const float* src = emb + (size_t)tok * HH + ce;
          f32x4 lo = *(const f32x4*)src;
          f32x4 hi = *(const f32x4*)(src + 4);
          i32x4 w;
          w[0] = pkh2(lo[0], lo[1]); w[1] = pkh2(lo[2], lo[3]);
          w[2] = pkh2(hi[0], hi[1]); w[3] = pkh2(hi[2], hi[3]);
          *(i32x4*)(&Alds[row * ALD + ce]) = w;
        }
      }
    }
  }

  if (layer == 1) {
    const size_t coff = (size_t)BB * TT * HH;
    const size_t hoff = coff + (size_t)BB * HH;
    f32x2 c2; c2[0] = cA; c2[1] = cB;
    f32x2 h2; h2[0] = hA; h2[1] = hB;
    *(f32x2*)(out + coff + (size_t)eb * HH + u0) = c2;
    *(f32x2*)(out + hoff + (size_t)eb * HH + u0) = h2;
  }
}

extern "C" void kernel_launch(void* const* d_in, const int* in_sizes, int n_in,
                              void* d_out, int out_size, void* d_ws, size_t ws_size,
                              hipStream_t stream) {
  (void)in_sizes; (void)n_in; (void)out_size; (void)ws_size;
  const int* tokens  = (const int*)d_in[0];
  const int* lengths = (const int*)d_in[1];
  const float* emb   = (const float*)d_in[2];
  const float* Wx    = (const float*)d_in[3];
  const float* Wh    = (const float*)d_in[4];
  const float* bias  = (const float*)d_in[5];

  // ws layout (~8.9 MB):
  //   [0, 4K)         flags [32] x 128B
  //   [4K, 4.5K)      ctl   [4] x 128B  (home, ctrA, ctrB, claimed)
  //   [4.5K, +256K)   htagL [2][2][32][256] u64
  //   [+256K)         htagG (same shape)
  //   then            ws_y  [32][256][512] u16
  char* w = (char*)d_ws;
  const size_t FB = (size_t)32 * FLGSTRIDE * 4;       // 4096
  const size_t CT = 512;
  const size_t HT = (size_t)2 * 2 * BB * 256 * 8;     // 262144
  unsigned int*   flags = (unsigned int*)w;
  unsigned int*   ctl   = (unsigned int*)(w + FB);
  u64*            htagL = (u64*)(w + FB + CT);
  u64*            htagG = (u64*)(w + FB + CT + HT);
  unsigned short* ws_y  = (unsigned short*)(w + FB + CT + 2 * HT);

  const int zero_words = (int)((FB + CT + 2 * HT) / 4);
  hipLaunchKernelGGL(zero_ws_kernel, dim3((zero_words + 255) / 256), dim3(256), 0, stream,
                     (unsigned int*)d_ws, zero_words);
  hipLaunchKernelGGL(lstm_enc_kernel, dim3(GRIDN), dim3(256), 0, stream,
                     tokens, lengths, emb, Wx, Wh, bias, (float*)d_out,
                     ws_y, htagL, htagG, flags, ctl);
}